// Round 13
// baseline (731.406 us; speedup 1.0000x reference)
//
#include <hip/hip_runtime.h>
#include <cstdint>

// HEADS=16, DIM=1024, SEQ=512, MEM=512, CMEM=128, RATIO=4, DIM_H=64, b=8, kv_len=1152

typedef __bf16 bf16;
typedef __bf16 bf16x2 __attribute__((ext_vector_type(2)));
typedef __bf16 bf16x4 __attribute__((ext_vector_type(4)));
typedef __bf16 bf16x8 __attribute__((ext_vector_type(8)));
typedef float  f32x2  __attribute__((ext_vector_type(2)));
typedef float  f32x4  __attribute__((ext_vector_type(4)));

// ---------------------------------------------------------------------------
// MFMA GEMM: C[M,N] = A[M,K] @ B[K,N], tile 128x128, BK=32, 4 waves.
// XCD-swizzled block order (bijective when nwg%8==0, else identity).
// ---------------------------------------------------------------------------
template<int AMODE, int EPI>
__global__ __launch_bounds__(256)
void mfma_gemm(const bf16* __restrict__ A, const bf16* __restrict__ B2,
               float* __restrict__ C, bf16* __restrict__ outB, bf16* __restrict__ vT,
               int N, int K, int lda, int ldbt, int ldc,
               const float* __restrict__ bias, int vrows,
               const bf16* __restrict__ gcmem, const bf16* __restrict__ gmem,
               const bf16* __restrict__ gx)
{
    int f = blockIdx.y * gridDim.x + blockIdx.x;
    int nwg = gridDim.x * gridDim.y;
    int wf = f;
    if ((nwg & 7) == 0) wf = (f & 7) * (nwg >> 3) + (f >> 3);
    int row0 = (wf / gridDim.x) * 128, col0 = (wf % gridDim.x) * 128;
    int tid = threadIdx.x;

    __shared__ bf16 As[128][72];
    __shared__ bf16 Bs[128][72];

    int rn_ = tid >> 2;           // 0..63
    int c8  = (tid & 3) * 8;      // k-chunk (bf16)

    const bf16* aptr[2];
#pragma unroll
    for (int jj = 0; jj < 2; jj++) {
        int gr = row0 + rn_ + 64 * jj;
        if (AMODE == 0) {
            aptr[jj] = A + (long)gr * lda;
        } else {
            int bb = gr / 1152, rr = gr - bb * 1152;
            aptr[jj] = (rr < 128) ? (gcmem + ((long)bb * 128 + rr) * 1024)
                     : (rr < 640) ? (gmem + ((long)bb * 512 + (rr - 128)) * 1024)
                                  : (gx   + ((long)bb * 512 + (rr - 640)) * 1024);
        }
    }
    const bf16* bptr[2];
#pragma unroll
    for (int jj = 0; jj < 2; jj++) {
        int gc = col0 + rn_ + 64 * jj;
        bptr[jj] = (gc < N) ? (B2 + (long)gc * ldbt + c8) : nullptr;
    }

    int lane = tid & 63, wid = tid >> 6;
    int wr = wid >> 1, wc = wid & 1;
    int fr = lane & 15, fq = lane >> 4;

    f32x4 acc[4][4];
#pragma unroll
    for (int i = 0; i < 4; i++)
#pragma unroll
        for (int j = 0; j < 4; j++) acc[i][j] = (f32x4){0.f, 0.f, 0.f, 0.f};

    for (int k0 = 0; k0 < K; k0 += 32) {
#pragma unroll
        for (int jj = 0; jj < 2; jj++) {
            bf16x8 v = *(const bf16x8*)(aptr[jj] + k0 + c8);
            *(bf16x8*)&As[rn_ + 64 * jj][c8] = v;
        }
#pragma unroll
        for (int jj = 0; jj < 2; jj++) {
            bf16x8 v = {};
            if (bptr[jj]) v = *(const bf16x8*)(bptr[jj] + k0);
            *(bf16x8*)&Bs[rn_ + 64 * jj][c8] = v;
        }
        __syncthreads();

        bf16x8 af[4], bfv[4];
#pragma unroll
        for (int i = 0; i < 4; i++)
            af[i] = *(const bf16x8*)&As[wr * 64 + i * 16 + fr][fq * 8];
#pragma unroll
        for (int j = 0; j < 4; j++)
            bfv[j] = *(const bf16x8*)&Bs[wc * 64 + j * 16 + fr][fq * 8];
#pragma unroll
        for (int i = 0; i < 4; i++)
#pragma unroll
            for (int j = 0; j < 4; j++)
                acc[i][j] = __builtin_amdgcn_mfma_f32_16x16x32_bf16(af[i], bfv[j], acc[i][j], 0, 0, 0);
        __syncthreads();
    }

#pragma unroll
    for (int i = 0; i < 4; i++) {
#pragma unroll
        for (int j = 0; j < 4; j++) {
#pragma unroll
            for (int g = 0; g < 4; g++) {
                int r = row0 + wr * 64 + i * 16 + fq * 4 + g;
                int c = col0 + wc * 64 + j * 16 + fr;
                float v = acc[i][j][g];
                if (EPI == 0) {
                    if (c < N) {
                        if (bias) v += bias[c];
                        C[(long)r * ldc + c] = v;
                    }
                } else if (EPI == 6) {
                    if (c < N) {
                        if (bias) v += bias[c];
                        __builtin_nontemporal_store(v, &C[(long)r * ldc + c]);
                    }
                } else if (EPI == 7) {
                    if (c < N) {
                        if (bias) v += bias[c];
                        C[(long)r * ldc + c] = v;
                        outB[(long)r * 1024 + c] = (bf16)v;
                    }
                } else if (EPI == 4) {
                    if (c < N) outB[(long)r * ldc + c] = (bf16)v;
                } else { // EPI == 5
                    if (c < 1024) {
                        outB[(long)r * 1024 + c] = (bf16)v;
                    } else {
                        int d = c - 1024; int hh = d >> 6; d &= 63;
                        int bb = r / vrows; int j2 = r - bb * vrows;
                        vT[(((long)(bb * 16 + hh)) * 64 + d) * vrows + j2] = (bf16)v;
                    }
                }
            }
        }
    }
}

// fp32 [R][C] -> bf16 [C][R]
__global__ __launch_bounds__(256)
void transpose_cast(const float* __restrict__ in, bf16* __restrict__ out, int R, int C)
{
    __shared__ float t[32][33];
    int c0 = blockIdx.x * 32, r0 = blockIdx.y * 32;
    int tx = threadIdx.x & 31, ty = threadIdx.x >> 5;
#pragma unroll
    for (int i = 0; i < 32; i += 8)
        t[ty + i][tx] = in[(long)(r0 + ty + i) * C + c0 + tx];
    __syncthreads();
#pragma unroll
    for (int i = 0; i < 32; i += 8)
        out[(long)(c0 + ty + i) * R + r0 + tx] = (bf16)t[tx][ty + i];
}

// conv_w [o][i][r] -> bf16 [o][r*1024+i], LDS-staged (coalesced global read)
__global__ __launch_bounds__(256)
void convw_cast(const float* __restrict__ cw, bf16* __restrict__ out)
{
    long o = blockIdx.x;
    const float* src = cw + o * 4096;
    bf16* dst = out + o * 4096;
    __shared__ float t[4096];
#pragma unroll
    for (int k = 0; k < 4; k++)
        *(f32x4*)&t[(threadIdx.x + k * 256) * 4] = *(const f32x4*)&src[(threadIdx.x + k * 256) * 4];
    __syncthreads();
#pragma unroll
    for (int k = 0; k < 8; k++) {
        int d2 = 2 * (threadIdx.x + k * 256);
        int pi = ((d2 & 1023) << 2) | (d2 >> 10);
        bf16x2 h = { (bf16)t[pi], (bf16)t[pi + 4] };
        *(bf16x2*)&dst[d2] = h;
    }
}

// elementwise fp32 -> bf16 (vectorized by 4)
__global__ __launch_bounds__(256)
void cast_f2b(const float* __restrict__ in, bf16* __restrict__ out, int n4)
{
    int i = blockIdx.x * 256 + threadIdx.x;
    int stride = gridDim.x * 256;
    for (; i < n4; i += stride) {
        float4 f = reinterpret_cast<const float4*>(in)[i];
        bf16x4 h = { (bf16)f.x, (bf16)f.y, (bf16)f.z, (bf16)f.w };
        reinterpret_cast<bf16x4*>(out)[i] = h;
    }
}

// ---------------------------------------------------------------------------
// Fused attention (round-12 structure, unchanged): 16 q-rows/block, 4 waves.
// ---------------------------------------------------------------------------
#define SSTR 1164

__global__ __launch_bounds__(256)
void attn_fused16(const bf16* __restrict__ qb, const bf16* __restrict__ kb,
                  const bf16* __restrict__ peb, const bf16* __restrict__ vTb,
                  float* __restrict__ weights, bf16* __restrict__ oatb)
{
    int bid = blockIdx.x;
    int w = (bid & 7) * 512 + (bid >> 3);
    int z = w >> 5;
    int b = z >> 4, h = z & 15;
    int r0 = (w & 31) * 16;
    int tid = threadIdx.x;
    int lane = tid & 63, wid = tid >> 6;
    int fr = lane & 15, fq = lane >> 4;

    __shared__ bf16 S[16 * SSTR];

    bf16x8 afr[2];
#pragma unroll
    for (int ks = 0; ks < 2; ks++)
        afr[ks] = *(const bf16x8*)&qb[((long)(b * 512 + r0 + fr)) * 1024 + h * 64 + ks * 32 + fq * 8];

#pragma unroll 3
    for (int ch = 0; ch < 9; ch++) {
        int c0 = ch * 128;
        int jb0 = c0 + 496 - r0 + 32 * wid;

        f32x4 p[3];
#pragma unroll
        for (int ct = 0; ct < 3; ct++) {
            f32x4 a = (f32x4){0.f, 0.f, 0.f, 0.f};
            int j = jb0 + ct * 16 + fr;
            bool ok = (j < 1152);
#pragma unroll
            for (int ks = 0; ks < 2; ks++) {
                bf16x8 bv = {};
                if (ok) bv = *(const bf16x8*)&peb[((long)(h * 1152 + j)) * 64 + ks * 32 + fq * 8];
                a = __builtin_amdgcn_mfma_f32_16x16x32_bf16(afr[ks], bv, a, 0, 0, 0);
            }
            p[ct] = a;
        }

#pragma unroll
        for (int tt = 0; tt < 2; tt++) {
            int cc = 32 * wid + 16 * tt + fr;
            f32x4 a = (f32x4){0.f, 0.f, 0.f, 0.f};
            long krow = (long)(b * 1152 + c0 + cc);
#pragma unroll
            for (int ks = 0; ks < 2; ks++) {
                bf16x8 bv = *(const bf16x8*)&kb[krow * 1024 + h * 64 + ks * 32 + fq * 8];
                a = __builtin_amdgcn_mfma_f32_16x16x32_bf16(afr[ks], bv, a, 0, 0, 0);
            }
#pragma unroll
            for (int g = 0; g < 4; g++) {
                int rr = fq * 4 + g;
                int uu = fr + 15 - rr;
                int src = (uu & 15) | (fq << 4);
                float s0 = __shfl(p[tt][g], src, 64);
                float s1 = __shfl(p[tt + 1][g], src, 64);
                float pv = (uu < 16) ? s0 : s1;
                S[rr * SSTR + c0 + cc] = (bf16)(0.125f * (a[g] + pv));
            }
        }
    }
    __syncthreads();

    for (int rw = 0; rw < 4; rw++) {
        int row = wid * 4 + rw;
        bf16* Srow = &S[row * SSTR];
        bf16x8 v0 = *(const bf16x8*)&Srow[lane * 8];
        bf16x8 v1 = *(const bf16x8*)&Srow[512 + lane * 8];
        bf16x2 v2 = *(const bf16x2*)&Srow[1024 + lane * 2];
        float e[18];
#pragma unroll
        for (int j = 0; j < 8; j++) { e[j] = (float)v0[j]; e[8 + j] = (float)v1[j]; }
        e[16] = (float)v2[0]; e[17] = (float)v2[1];

        float m = e[0];
#pragma unroll
        for (int k = 1; k < 18; k++) m = fmaxf(m, e[k]);
#pragma unroll
        for (int off = 32; off; off >>= 1) m = fmaxf(m, __shfl_xor(m, off, 64));
        float sm = 0.f;
#pragma unroll
        for (int k = 0; k < 18; k++) { e[k] = __expf(e[k] - m); sm += e[k]; }
#pragma unroll
        for (int off = 32; off; off >>= 1) sm += __shfl_xor(sm, off, 64);
        float inv = 1.f / sm;

        bf16x8 w0, w1; bf16x2 w2;
#pragma unroll
        for (int j = 0; j < 8; j++) { w0[j] = (bf16)(e[j] * inv); w1[j] = (bf16)(e[8 + j] * inv); }
        w2[0] = (bf16)(e[16] * inv); w2[1] = (bf16)(e[17] * inv);
        *(bf16x8*)&Srow[lane * 8] = w0;
        *(bf16x8*)&Srow[512 + lane * 8] = w1;
        *(bf16x2*)&Srow[1024 + lane * 2] = w2;
    }
    __syncthreads();

    f32x4 oacc = (f32x4){0.f, 0.f, 0.f, 0.f};
    int dt = wid;
    for (int ch = 0; ch < 9; ch++) {
        int c0 = ch * 128;
#pragma unroll
        for (int ks = 0; ks < 4; ks++) {
            bf16x8 pa = *(const bf16x8*)&S[fr * SSTR + c0 + ks * 32 + fq * 8];
            bf16x8 vb = *(const bf16x8*)&vTb[((long)z * 64 + dt * 16 + fr) * 1152 + c0 + ks * 32 + fq * 8];
            oacc = __builtin_amdgcn_mfma_f32_16x16x32_bf16(pa, vb, oacc, 0, 0, 0);
        }
    }
#pragma unroll
    for (int g = 0; g < 4; g++)
        oatb[((long)(b * 512 + r0 + fq * 4 + g)) * 1024 + h * 64 + dt * 16 + fr] = (bf16)oacc[g];

    for (int rw = 0; rw < 4; rw++) {
        int row = wid * 4 + rw;
        const bf16* Srow = &S[row * SSTR];
        long wbase = ((long)z * 512 + r0 + row) * 1152;
        bf16x8 v0 = *(const bf16x8*)&Srow[lane * 8];
        bf16x8 v1 = *(const bf16x8*)&Srow[512 + lane * 8];
        bf16x2 v2 = *(const bf16x2*)&Srow[1024 + lane * 2];
        f32x4 a0 = { (float)v0[0], (float)v0[1], (float)v0[2], (float)v0[3] };
        f32x4 a1 = { (float)v0[4], (float)v0[5], (float)v0[6], (float)v0[7] };
        f32x4 b0 = { (float)v1[0], (float)v1[1], (float)v1[2], (float)v1[3] };
        f32x4 b1 = { (float)v1[4], (float)v1[5], (float)v1[6], (float)v1[7] };
        f32x2 c0 = { (float)v2[0], (float)v2[1] };
        *(f32x4*)&weights[wbase + lane * 8] = a0;
        *(f32x4*)&weights[wbase + lane * 8 + 4] = a1;
        *(f32x4*)&weights[wbase + 512 + lane * 8] = b0;
        *(f32x4*)&weights[wbase + 512 + lane * 8 + 4] = b1;
        *(f32x2*)&weights[wbase + 1024 + lane * 2] = c0;
    }
}

// ---------------------------------------------------------------------------
// Fused aux loss v2 (attn-style): 16 q-rows/block, 4096 blocks, XCD swizzle,
// direct-global fragments, S1(16x512)/S2(16x128) in ~21 KB LDS, 5 barriers.
// ---------------------------------------------------------------------------
#define S1STR 524
#define S2STR 140

__global__ __launch_bounds__(256)
void aux_fused16(const bf16* __restrict__ qb, const bf16* __restrict__ kb,
                 const bf16* __restrict__ ckb,
                 const bf16* __restrict__ vTb, const bf16* __restrict__ cvT,
                 float* __restrict__ partials)
{
    int bid = blockIdx.x;
    int w = (bid & 7) * 512 + (bid >> 3);
    int z = w >> 5;
    int b = z >> 4, h = z & 15;
    int r0 = (w & 31) * 16;
    int tid = threadIdx.x;
    int lane = tid & 63, wid = tid >> 6;
    int fr = lane & 15, fq = lane >> 4;

    __shared__ bf16 S1[16 * S1STR];   // 16.4 KB
    __shared__ bf16 S2[16 * S2STR];   // 4.4 KB
    __shared__ float wred[4];

    // q fragments
    bf16x8 afr[2];
#pragma unroll
    for (int ks = 0; ks < 2; ks++)
        afr[ks] = *(const bf16x8*)&qb[((long)(b * 512 + r0 + fr)) * 1024 + h * 64 + ks * 32 + fq * 8];

    // ---- S1 build: mem attention scores (kv rows 128..639), 4 chunks ----
#pragma unroll
    for (int ch = 0; ch < 4; ch++) {
#pragma unroll
        for (int tt = 0; tt < 2; tt++) {
            int cc = 32 * wid + 16 * tt + fr;
            f32x4 a = (f32x4){0.f, 0.f, 0.f, 0.f};
            long krow = (long)(b * 1152 + 128 + ch * 128 + cc);
#pragma unroll
            for (int ks = 0; ks < 2; ks++) {
                bf16x8 bv = *(const bf16x8*)&kb[krow * 1024 + h * 64 + ks * 32 + fq * 8];
                a = __builtin_amdgcn_mfma_f32_16x16x32_bf16(afr[ks], bv, a, 0, 0, 0);
            }
#pragma unroll
            for (int g = 0; g < 4; g++)
                S1[(fq * 4 + g) * S1STR + ch * 128 + cc] = (bf16)(0.125f * a[g]);
        }
    }
    __syncthreads();

    // ---- softmax over 512 (4 rows/wave, vectorized) ----
    for (int rw = 0; rw < 4; rw++) {
        int row = wid * 4 + rw;
        bf16* Srow = &S1[row * S1STR];
        bf16x8 v0 = *(const bf16x8*)&Srow[lane * 8];
        float e[8];
#pragma unroll
        for (int j = 0; j < 8; j++) e[j] = (float)v0[j];
        float m = e[0];
#pragma unroll
        for (int k = 1; k < 8; k++) m = fmaxf(m, e[k]);
#pragma unroll
        for (int off = 32; off; off >>= 1) m = fmaxf(m, __shfl_xor(m, off, 64));
        float sm = 0.f;
#pragma unroll
        for (int k = 0; k < 8; k++) { e[k] = __expf(e[k] - m); sm += e[k]; }
#pragma unroll
        for (int off = 32; off; off >>= 1) sm += __shfl_xor(sm, off, 64);
        float inv = 1.f / sm;
        bf16x8 w0;
#pragma unroll
        for (int j = 0; j < 8; j++) w0[j] = (bf16)(e[j] * inv);
        *(bf16x8*)&Srow[lane * 8] = w0;
    }
    __syncthreads();

    // ---- PV1 (V rows 128..639 via vTb cols +128) ----
    f32x4 o1 = (f32x4){0.f, 0.f, 0.f, 0.f};
#pragma unroll
    for (int ch = 0; ch < 4; ch++) {
#pragma unroll
        for (int ks = 0; ks < 4; ks++) {
            bf16x8 pa = *(const bf16x8*)&S1[fr * S1STR + ch * 128 + ks * 32 + fq * 8];
            bf16x8 vb = *(const bf16x8*)&vTb[((long)z * 64 + wid * 16 + fr) * 1152 + 128 + ch * 128 + ks * 32 + fq * 8];
            o1 = __builtin_amdgcn_mfma_f32_16x16x32_bf16(pa, vb, o1, 0, 0, 0);
        }
    }

    // ---- S2 build: compressed attention scores (128 cols) ----
#pragma unroll
    for (int tt = 0; tt < 2; tt++) {
        int cc = 32 * wid + 16 * tt + fr;
        f32x4 a = (f32x4){0.f, 0.f, 0.f, 0.f};
#pragma unroll
        for (int ks = 0; ks < 2; ks++) {
            bf16x8 bv = *(const bf16x8*)&ckb[((long)(b * 128 + cc)) * 1024 + h * 64 + ks * 32 + fq * 8];
            a = __builtin_amdgcn_mfma_f32_16x16x32_bf16(afr[ks], bv, a, 0, 0, 0);
        }
#pragma unroll
        for (int g = 0; g < 4; g++)
            S2[(fq * 4 + g) * S2STR + cc] = (bf16)(0.125f * a[g]);
    }
    __syncthreads();

    // ---- softmax over 128 (2 cols/lane) ----
    for (int rw = 0; rw < 4; rw++) {
        int row = wid * 4 + rw;
        bf16* Srow = &S2[row * S2STR];
        bf16x2 v = *(const bf16x2*)&Srow[lane * 2];
        float e0 = (float)v[0], e1 = (float)v[1];
        float m = fmaxf(e0, e1);
#pragma unroll
        for (int off = 32; off; off >>= 1) m = fmaxf(m, __shfl_xor(m, off, 64));
        e0 = __expf(e0 - m); e1 = __expf(e1 - m);
        float sm = e0 + e1;
#pragma unroll
        for (int off = 32; off; off >>= 1) sm += __shfl_xor(sm, off, 64);
        float inv = 1.f / sm;
        bf16x2 w2 = { (bf16)(e0 * inv), (bf16)(e1 * inv) };
        *(bf16x2*)&Srow[lane * 2] = w2;
    }
    __syncthreads();

    // ---- PV2 ----
    f32x4 o2 = (f32x4){0.f, 0.f, 0.f, 0.f};
#pragma unroll
    for (int ks = 0; ks < 4; ks++) {
        bf16x8 pa = *(const bf16x8*)&S2[fr * S2STR + ks * 32 + fq * 8];
        bf16x8 vb = *(const bf16x8*)&cvT[((long)z * 64 + wid * 16 + fr) * 128 + ks * 32 + fq * 8];
        o2 = __builtin_amdgcn_mfma_f32_16x16x32_bf16(pa, vb, o2, 0, 0, 0);
    }

    // ---- squared diff + reduce ----
    float local = 0.f;
#pragma unroll
    for (int g = 0; g < 4; g++) { float dd = o1[g] - o2[g]; local += dd * dd; }
#pragma unroll
    for (int off = 32; off; off >>= 1) local += __shfl_xor(local, off, 64);
    if (lane == 0) wred[wid] = local;
    __syncthreads();
    if (tid == 0)
        partials[bid] = wred[0] + wred[1] + wred[2] + wred[3];
}

__global__ __launch_bounds__(256)
void aux_reduce_kernel(const float* __restrict__ partials, float* __restrict__ out)
{
    int tid = threadIdx.x;
    __shared__ float wred[4];
    float s = 0.f;
    for (int i = tid; i < 4096; i += 256) s += partials[i];
#pragma unroll
    for (int off = 32; off; off >>= 1) s += __shfl_xor(s, off, 64);
    if ((tid & 63) == 0) wred[tid >> 6] = s;
    __syncthreads();
    if (tid == 0) out[0] = (wred[0] + wred[1] + wred[2] + wred[3]) * (1.0f / 4194304.0f);
}

__global__ __launch_bounds__(256)
void copy_kernel(float* __restrict__ dst, const float* __restrict__ src, int n4)
{
    int i = blockIdx.x * 256 + threadIdx.x;
    int stride = gridDim.x * 256;
    for (; i < n4; i += stride) {
        f32x4 v = reinterpret_cast<const f32x4*>(src)[i];
        __builtin_nontemporal_store(v, &reinterpret_cast<f32x4*>(dst)[i]);
    }
}

extern "C" void kernel_launch(void* const* d_in, const int* in_sizes, int n_in,
                              void* d_out, int out_size, void* d_ws, size_t ws_size,
                              hipStream_t stream)
{
    const float* x      = (const float*)d_in[0];
    const float* mem    = (const float*)d_in[1];
    const float* cmem   = (const float*)d_in[2];
    const float* pe     = (const float*)d_in[3];
    const float* Wq     = (const float*)d_in[4];
    const float* Wkv    = (const float*)d_in[5];
    const float* Wout   = (const float*)d_in[6];
    const float* bout   = (const float*)d_in[7];
    const float* conv_w = (const float*)d_in[8];
    const float* conv_b = (const float*)d_in[9];

    float* out_logits  = (float*)d_out;                 // 8*512*1024
    float* out_newmem  = out_logits + 4194304;          // 8*512*1024
    float* out_newcmem = out_newmem + 4194304;          // 8*128*1024
    float* out_aux     = out_newcmem + 1048576;         // 1
    float* out_weights = out_aux + 1;                   // 8*16*512*1152

    float* ws       = (float*)d_ws;
    float* partials = ws;                    // 4096 f
    bf16* bws     = (bf16*)(partials + 4096);
    bf16* WqTb    = bws;                     // 1,048,576
    bf16* WkvTb   = WqTb + 1048576;          // 2,097,152
    bf16* WoutTb  = WkvTb + 2097152;         // 1,048,576
    bf16* convwTb = WoutTb + 1048576;        // 4,194,304
    bf16* vTb     = convwTb + 4194304;       // 9,437,184
    bf16* cvT     = vTb + 9437184;           // 1,048,576
    bf16* qb      = cvT + 1048576;           // 4,194,304
    bf16* kb      = qb + 4194304;            // 9,437,184
    bf16* ckb     = kb + 9437184;            // 1,048,576
    bf16* peb     = ckb + 1048576;           // 1,179,648
    bf16* xb      = peb + 1179648;           // 4,194,304
    bf16* memb    = xb + 4194304;            // 4,194,304
    bf16* cmemb   = memb + 4194304;          // 1,048,576
    bf16* ncmemb  = cmemb + 1048576;         // 1,048,576
    bf16* oatb    = ncmemb + 1048576;        // 4,194,304

    dim3 blk(256);

    transpose_cast<<<dim3(32, 32), blk, 0, stream>>>(Wq, WqTb, 1024, 1024);
    transpose_cast<<<dim3(64, 32), blk, 0, stream>>>(Wkv, WkvTb, 1024, 2048);
    transpose_cast<<<dim3(32, 32), blk, 0, stream>>>(Wout, WoutTb, 1024, 1024);
    convw_cast<<<dim3(1024), blk, 0, stream>>>(conv_w, convwTb);
    cast_f2b<<<dim3(1152), blk, 0, stream>>>(pe, peb, 294912);
    cast_f2b<<<dim3(2048), blk, 0, stream>>>(x, xb, 1048576);
    cast_f2b<<<dim3(2048), blk, 0, stream>>>(mem, memb, 1048576);
    cast_f2b<<<dim3(1024), blk, 0, stream>>>(cmem, cmemb, 262144);

    // qb = bf16(x @ Wq)
    mfma_gemm<0, 4><<<dim3(8, 32, 1), blk, 0, stream>>>(
        xb, WqTb, nullptr, qb, nullptr, 1024, 1024, 1024, 1024, 1024,
        nullptr, 0, nullptr, nullptr, nullptr);

    // kb/vTb = bf16(concat(cmem,mem,x) @ Wkv)
    mfma_gemm<1, 5><<<dim3(16, 72, 1), blk, 0, stream>>>(
        nullptr, WkvTb, nullptr, kb, vTb, 2048, 1024, 1024, 1024, 2048,
        nullptr, 1152, cmemb, memb, xb);

    // new_cmem = mem[1024x4096] @ convwT + conv_b  (fp32 output + bf16 ncmemb)
    mfma_gemm<0, 7><<<dim3(8, 8, 1), blk, 0, stream>>>(
        memb, convwTb, out_newcmem, ncmemb, nullptr, 1024, 4096, 4096, 4096, 1024,
        conv_b, 0, nullptr, nullptr, nullptr);

    // ckb/cvT = bf16(new_cmem @ Wkv)
    mfma_gemm<0, 5><<<dim3(16, 8, 1), blk, 0, stream>>>(
        ncmemb, WkvTb, nullptr, ckb, cvT, 2048, 1024, 1024, 1024, 2048,
        nullptr, 128, nullptr, nullptr, nullptr);

    // fused attention with XCD-chunked swizzle
    attn_fused16<<<dim3(4096), blk, 0, stream>>>(qb, kb, peb, vTb, out_weights, oatb);

    // logits = oat @ Wout + bout (non-temporal output)
    mfma_gemm<0, 6><<<dim3(8, 32, 1), blk, 0, stream>>>(
        oatb, WoutTb, out_logits, nullptr, nullptr, 1024, 1024, 1024, 1024, 1024,
        bout, 0, nullptr, nullptr, nullptr);

    // new_mem = x (non-temporal)
    copy_kernel<<<dim3(4096), blk, 0, stream>>>(out_newmem, x, 1048576);

    // aux loss v2
    aux_fused16<<<dim3(4096), blk, 0, stream>>>(qb, kb, ckb, vTb, cvT, partials);
    aux_reduce_kernel<<<dim3(1), blk, 0, stream>>>(partials, out_aux);
}

// Round 14
// 718.215 us; speedup vs baseline: 1.0184x; 1.0184x over previous
//
#include <hip/hip_runtime.h>
#include <cstdint>

// HEADS=16, DIM=1024, SEQ=512, MEM=512, CMEM=128, RATIO=4, DIM_H=64, b=8, kv_len=1152

typedef __bf16 bf16;
typedef __bf16 bf16x2 __attribute__((ext_vector_type(2)));
typedef __bf16 bf16x4 __attribute__((ext_vector_type(4)));
typedef __bf16 bf16x8 __attribute__((ext_vector_type(8)));
typedef float  f32x2  __attribute__((ext_vector_type(2)));
typedef float  f32x4  __attribute__((ext_vector_type(4)));

// ---------------------------------------------------------------------------
// MFMA GEMM: C[M,N] = A[M,K] @ B[K,N], tile 128x128, BK=32, 4 waves.
// (no block swizzle — round-13 A/B showed it regressed)
// ---------------------------------------------------------------------------
template<int AMODE, int EPI>
__global__ __launch_bounds__(256)
void mfma_gemm(const bf16* __restrict__ A, const bf16* __restrict__ B2,
               float* __restrict__ C, bf16* __restrict__ outB, bf16* __restrict__ vT,
               int N, int K, int lda, int ldbt, int ldc,
               const float* __restrict__ bias, int vrows,
               const bf16* __restrict__ gcmem, const bf16* __restrict__ gmem,
               const bf16* __restrict__ gx)
{
    int row0 = blockIdx.y * 128, col0 = blockIdx.x * 128;
    int tid = threadIdx.x;

    __shared__ bf16 As[128][72];
    __shared__ bf16 Bs[128][72];

    int rn_ = tid >> 2;           // 0..63
    int c8  = (tid & 3) * 8;      // k-chunk (bf16)

    const bf16* aptr[2];
#pragma unroll
    for (int jj = 0; jj < 2; jj++) {
        int gr = row0 + rn_ + 64 * jj;
        if (AMODE == 0) {
            aptr[jj] = A + (long)gr * lda;
        } else {
            int bb = gr / 1152, rr = gr - bb * 1152;
            aptr[jj] = (rr < 128) ? (gcmem + ((long)bb * 128 + rr) * 1024)
                     : (rr < 640) ? (gmem + ((long)bb * 512 + (rr - 128)) * 1024)
                                  : (gx   + ((long)bb * 512 + (rr - 640)) * 1024);
        }
    }
    const bf16* bptr[2];
#pragma unroll
    for (int jj = 0; jj < 2; jj++) {
        int gc = col0 + rn_ + 64 * jj;
        bptr[jj] = (gc < N) ? (B2 + (long)gc * ldbt + c8) : nullptr;
    }

    int lane = tid & 63, wid = tid >> 6;
    int wr = wid >> 1, wc = wid & 1;
    int fr = lane & 15, fq = lane >> 4;

    f32x4 acc[4][4];
#pragma unroll
    for (int i = 0; i < 4; i++)
#pragma unroll
        for (int j = 0; j < 4; j++) acc[i][j] = (f32x4){0.f, 0.f, 0.f, 0.f};

    for (int k0 = 0; k0 < K; k0 += 32) {
#pragma unroll
        for (int jj = 0; jj < 2; jj++) {
            bf16x8 v = *(const bf16x8*)(aptr[jj] + k0 + c8);
            *(bf16x8*)&As[rn_ + 64 * jj][c8] = v;
        }
#pragma unroll
        for (int jj = 0; jj < 2; jj++) {
            bf16x8 v = {};
            if (bptr[jj]) v = *(const bf16x8*)(bptr[jj] + k0);
            *(bf16x8*)&Bs[rn_ + 64 * jj][c8] = v;
        }
        __syncthreads();

        bf16x8 af[4], bfv[4];
#pragma unroll
        for (int i = 0; i < 4; i++)
            af[i] = *(const bf16x8*)&As[wr * 64 + i * 16 + fr][fq * 8];
#pragma unroll
        for (int j = 0; j < 4; j++)
            bfv[j] = *(const bf16x8*)&Bs[wc * 64 + j * 16 + fr][fq * 8];
#pragma unroll
        for (int i = 0; i < 4; i++)
#pragma unroll
            for (int j = 0; j < 4; j++)
                acc[i][j] = __builtin_amdgcn_mfma_f32_16x16x32_bf16(af[i], bfv[j], acc[i][j], 0, 0, 0);
        __syncthreads();
    }

#pragma unroll
    for (int i = 0; i < 4; i++) {
#pragma unroll
        for (int j = 0; j < 4; j++) {
#pragma unroll
            for (int g = 0; g < 4; g++) {
                int r = row0 + wr * 64 + i * 16 + fq * 4 + g;
                int c = col0 + wc * 64 + j * 16 + fr;
                float v = acc[i][j][g];
                if (EPI == 0) {
                    if (c < N) {
                        if (bias) v += bias[c];
                        C[(long)r * ldc + c] = v;
                    }
                } else if (EPI == 6) {
                    if (c < N) {
                        if (bias) v += bias[c];
                        __builtin_nontemporal_store(v, &C[(long)r * ldc + c]);
                    }
                } else if (EPI == 7) {
                    if (c < N) {
                        if (bias) v += bias[c];
                        C[(long)r * ldc + c] = v;
                        outB[(long)r * 1024 + c] = (bf16)v;
                    }
                } else if (EPI == 4) {
                    if (c < N) outB[(long)r * ldc + c] = (bf16)v;
                } else { // EPI == 5
                    if (c < 1024) {
                        outB[(long)r * 1024 + c] = (bf16)v;
                    } else {
                        int d = c - 1024; int hh = d >> 6; d &= 63;
                        int bb = r / vrows; int j2 = r - bb * vrows;
                        vT[(((long)(bb * 16 + hh)) * 64 + d) * vrows + j2] = (bf16)v;
                    }
                }
            }
        }
    }
}

// fp32 [R][C] -> bf16 [C][R]
__global__ __launch_bounds__(256)
void transpose_cast(const float* __restrict__ in, bf16* __restrict__ out, int R, int C)
{
    __shared__ float t[32][33];
    int c0 = blockIdx.x * 32, r0 = blockIdx.y * 32;
    int tx = threadIdx.x & 31, ty = threadIdx.x >> 5;
#pragma unroll
    for (int i = 0; i < 32; i += 8)
        t[ty + i][tx] = in[(long)(r0 + ty + i) * C + c0 + tx];
    __syncthreads();
#pragma unroll
    for (int i = 0; i < 32; i += 8)
        out[(long)(c0 + ty + i) * R + r0 + tx] = (bf16)t[tx][ty + i];
}

// conv_w [o][i][r] -> bf16 [o][r*1024+i], LDS-staged (coalesced global read)
__global__ __launch_bounds__(256)
void convw_cast(const float* __restrict__ cw, bf16* __restrict__ out)
{
    long o = blockIdx.x;
    const float* src = cw + o * 4096;
    bf16* dst = out + o * 4096;
    __shared__ float t[4096];
#pragma unroll
    for (int k = 0; k < 4; k++)
        *(f32x4*)&t[(threadIdx.x + k * 256) * 4] = *(const f32x4*)&src[(threadIdx.x + k * 256) * 4];
    __syncthreads();
#pragma unroll
    for (int k = 0; k < 8; k++) {
        int d2 = 2 * (threadIdx.x + k * 256);
        int pi = ((d2 & 1023) << 2) | (d2 >> 10);
        bf16x2 h = { (bf16)t[pi], (bf16)t[pi + 4] };
        *(bf16x2*)&dst[d2] = h;
    }
}

// elementwise fp32 -> bf16 (vectorized by 4)
__global__ __launch_bounds__(256)
void cast_f2b(const float* __restrict__ in, bf16* __restrict__ out, int n4)
{
    int i = blockIdx.x * 256 + threadIdx.x;
    int stride = gridDim.x * 256;
    for (; i < n4; i += stride) {
        float4 f = reinterpret_cast<const float4*>(in)[i];
        bf16x4 h = { (bf16)f.x, (bf16)f.y, (bf16)f.z, (bf16)f.w };
        reinterpret_cast<bf16x4*>(out)[i] = h;
    }
}

// ---------------------------------------------------------------------------
// Fused attention v4: 16 q-rows/block, 8 waves (512 thr), XCD swizzle.
// Each wave owns a 16-col slice per 128-chunk (2 pos tiles + 1 qk tile).
// After softmax: waves 0-3 do PV, waves 4-7 stream weights NT stores.
// LDS = S only (37.2 KB) -> 4 blocks/CU x 8 waves = 32 waves/CU (max).
// ---------------------------------------------------------------------------
#define SSTR 1164

__global__ __launch_bounds__(512)
void attn_fused16(const bf16* __restrict__ qb, const bf16* __restrict__ kb,
                  const bf16* __restrict__ peb, const bf16* __restrict__ vTb,
                  float* __restrict__ weights, bf16* __restrict__ oatb)
{
    // bijective XCD swizzle: 4096 blocks = 8 XCD x 512; z-major within XCD
    int bid = blockIdx.x;
    int w = (bid & 7) * 512 + (bid >> 3);
    int z = w >> 5;                  // b*16 + h
    int b = z >> 4, h = z & 15;
    int r0 = (w & 31) * 16;
    int tid = threadIdx.x;
    int lane = tid & 63, wid = tid >> 6;   // 0..7
    int fr = lane & 15, fq = lane >> 4;

    __shared__ bf16 S[16 * SSTR];      // 37.2 KB

    // q fragments direct from global
    bf16x8 afr[2];
#pragma unroll
    for (int ks = 0; ks < 2; ks++)
        afr[ks] = *(const bf16x8*)&qb[((long)(b * 512 + r0 + fr)) * 1024 + h * 64 + ks * 32 + fq * 8];

    // ---------------- S build: 9 chunks; wave owns cols [16w, 16w+16) ----------------
#pragma unroll 3
    for (int ch = 0; ch < 9; ch++) {
        int c0 = ch * 128;
        int jb0 = c0 + 16 * wid + 496 - r0;   // band start for this 16-col slice

        // 2 pos tiles covering band cols [0, 32)
        f32x4 p[2];
#pragma unroll
        for (int ct = 0; ct < 2; ct++) {
            f32x4 a = (f32x4){0.f, 0.f, 0.f, 0.f};
            int j = jb0 + ct * 16 + fr;
            bool ok = (j < 1152);
#pragma unroll
            for (int ks = 0; ks < 2; ks++) {
                bf16x8 bv = {};
                if (ok) bv = *(const bf16x8*)&peb[((long)(h * 1152 + j)) * 64 + ks * 32 + fq * 8];
                a = __builtin_amdgcn_mfma_f32_16x16x32_bf16(afr[ks], bv, a, 0, 0, 0);
            }
            p[ct] = a;
        }

        // 1 qk tile (cols c0+16w .. +16); shifted pos via cross-lane shuffle
        {
            int cc = 16 * wid + fr;
            f32x4 a = (f32x4){0.f, 0.f, 0.f, 0.f};
            long krow = (long)(b * 1152 + c0 + cc);
#pragma unroll
            for (int ks = 0; ks < 2; ks++) {
                bf16x8 bv = *(const bf16x8*)&kb[krow * 1024 + h * 64 + ks * 32 + fq * 8];
                a = __builtin_amdgcn_mfma_f32_16x16x32_bf16(afr[ks], bv, a, 0, 0, 0);
            }
#pragma unroll
            for (int g = 0; g < 4; g++) {
                int rr = fq * 4 + g;
                int uu = fr + 15 - rr;                 // 0..30
                int src = (uu & 15) | (fq << 4);
                float s0 = __shfl(p[0][g], src, 64);
                float s1 = __shfl(p[1][g], src, 64);
                float pv = (uu < 16) ? s0 : s1;
                S[rr * SSTR + c0 + cc] = (bf16)(0.125f * (a[g] + pv));
            }
        }
    }
    __syncthreads();

    // ---------------- softmax: 8 waves x 2 rows, vectorized LDS ----------------
    for (int rw = 0; rw < 2; rw++) {
        int row = wid * 2 + rw;
        bf16* Srow = &S[row * SSTR];
        bf16x8 v0 = *(const bf16x8*)&Srow[lane * 8];
        bf16x8 v1 = *(const bf16x8*)&Srow[512 + lane * 8];
        bf16x2 v2 = *(const bf16x2*)&Srow[1024 + lane * 2];
        float e[18];
#pragma unroll
        for (int j = 0; j < 8; j++) { e[j] = (float)v0[j]; e[8 + j] = (float)v1[j]; }
        e[16] = (float)v2[0]; e[17] = (float)v2[1];

        float m = e[0];
#pragma unroll
        for (int k = 1; k < 18; k++) m = fmaxf(m, e[k]);
#pragma unroll
        for (int off = 32; off; off >>= 1) m = fmaxf(m, __shfl_xor(m, off, 64));
        float sm = 0.f;
#pragma unroll
        for (int k = 0; k < 18; k++) { e[k] = __expf(e[k] - m); sm += e[k]; }
#pragma unroll
        for (int off = 32; off; off >>= 1) sm += __shfl_xor(sm, off, 64);
        float inv = 1.f / sm;

        bf16x8 w0, w1; bf16x2 w2;
#pragma unroll
        for (int j = 0; j < 8; j++) { w0[j] = (bf16)(e[j] * inv); w1[j] = (bf16)(e[8 + j] * inv); }
        w2[0] = (bf16)(e[16] * inv); w2[1] = (bf16)(e[17] * inv);
        *(bf16x8*)&Srow[lane * 8] = w0;
        *(bf16x8*)&Srow[512 + lane * 8] = w1;
        *(bf16x2*)&Srow[1024 + lane * 2] = w2;
    }
    __syncthreads();

    // ---------------- role split: waves 0-3 PV, waves 4-7 weights stores ----------------
    if (wid < 4) {
        f32x4 oacc = (f32x4){0.f, 0.f, 0.f, 0.f};
        int dt = wid;
        for (int ch = 0; ch < 9; ch++) {
            int c0 = ch * 128;
#pragma unroll
            for (int ks = 0; ks < 4; ks++) {
                bf16x8 pa = *(const bf16x8*)&S[fr * SSTR + c0 + ks * 32 + fq * 8];
                bf16x8 vb = *(const bf16x8*)&vTb[((long)z * 64 + dt * 16 + fr) * 1152 + c0 + ks * 32 + fq * 8];
                oacc = __builtin_amdgcn_mfma_f32_16x16x32_bf16(pa, vb, oacc, 0, 0, 0);
            }
        }
#pragma unroll
        for (int g = 0; g < 4; g++)
            oatb[((long)(b * 512 + r0 + fq * 4 + g)) * 1024 + h * 64 + dt * 16 + fr] = (bf16)oacc[g];
    } else {
        int w4 = wid - 4;
        for (int rw = 0; rw < 4; rw++) {
            int row = w4 * 4 + rw;
            const bf16* Srow = &S[row * SSTR];
            long wbase = ((long)z * 512 + r0 + row) * 1152;
            bf16x8 v0 = *(const bf16x8*)&Srow[lane * 8];
            bf16x8 v1 = *(const bf16x8*)&Srow[512 + lane * 8];
            bf16x2 v2 = *(const bf16x2*)&Srow[1024 + lane * 2];
            f32x4 a0 = { (float)v0[0], (float)v0[1], (float)v0[2], (float)v0[3] };
            f32x4 a1 = { (float)v0[4], (float)v0[5], (float)v0[6], (float)v0[7] };
            f32x4 b0 = { (float)v1[0], (float)v1[1], (float)v1[2], (float)v1[3] };
            f32x4 b1 = { (float)v1[4], (float)v1[5], (float)v1[6], (float)v1[7] };
            f32x2 c0 = { (float)v2[0], (float)v2[1] };
            __builtin_nontemporal_store(a0, (f32x4*)&weights[wbase + lane * 8]);
            __builtin_nontemporal_store(a1, (f32x4*)&weights[wbase + lane * 8 + 4]);
            __builtin_nontemporal_store(b0, (f32x4*)&weights[wbase + 512 + lane * 8]);
            __builtin_nontemporal_store(b1, (f32x4*)&weights[wbase + 512 + lane * 8 + 4]);
            __builtin_nontemporal_store(c0, (f32x2*)&weights[wbase + 1024 + lane * 2]);
        }
    }
}

// ---------------------------------------------------------------------------
// Fused MFMA aux loss (round-10 version, verified)
// ---------------------------------------------------------------------------
__global__ __launch_bounds__(256)
void aux_mfma_kernel(const bf16* __restrict__ qb, const bf16* __restrict__ kb,
                     const bf16* __restrict__ ckb,
                     const bf16* __restrict__ vTb, const bf16* __restrict__ cvT,
                     float* __restrict__ partials)
{
    int z = blockIdx.y;
    int b = z >> 4, h = z & 15;
    int r0 = blockIdx.x * 128;
    int tid = threadIdx.x;
    int lane = tid & 63, wid = tid >> 6;
    int fr = lane & 15, fq = lane >> 4;

    __shared__ bf16 qs[128][72];
    __shared__ bf16 upool[128 * 136];
    __shared__ bf16 vt[64][136];
    __shared__ float wred[4];

#pragma unroll
    for (int t = 0; t < 4; t++) {
        int e = tid + 256 * t; int rr = e >> 3, c8 = (e & 7) * 8;
        *(bf16x8*)&qs[rr][c8] = *(const bf16x8*)&qb[((long)(b * 512 + r0 + rr)) * 1024 + h * 64 + c8];
    }

    float o1[2][4][4];
    f32x4 oaccv[2][4];
    float mrow[2][4], lrow[2][4];
    f32x4 sacc[2][8];
    float local = 0.f;

    for (int pass = 0; pass < 2; pass++) {
#pragma unroll
        for (int i = 0; i < 2; i++)
#pragma unroll
            for (int g = 0; g < 4; g++) { mrow[i][g] = -3.4e38f; lrow[i][g] = 0.f; }
#pragma unroll
        for (int i = 0; i < 2; i++)
#pragma unroll
            for (int jd = 0; jd < 4; jd++) oaccv[i][jd] = (f32x4){0.f, 0.f, 0.f, 0.f};

        int nchunk = pass ? 1 : 4;
        for (int jt = 0; jt < nchunk; jt++) {
            __syncthreads();
            if (pass == 0) {
                long base = (long)(b * 1152 + 128 + jt * 128);
#pragma unroll
                for (int t = 0; t < 4; t++) {
                    int e = tid + 256 * t; int j = e >> 3, c8 = (e & 7) * 8;
                    *(bf16x8*)&upool[j * 72 + c8] = *(const bf16x8*)&kb[(base + j) * 1024 + h * 64 + c8];
                }
#pragma unroll
                for (int t = 0; t < 4; t++) {
                    int e = tid + 256 * t; int d = e >> 4, j8 = (e & 15) * 8;
                    *(bf16x8*)&vt[d][j8] =
                        *(const bf16x8*)&vTb[((long)z * 64 + d) * 1152 + 128 + jt * 128 + j8];
                }
            } else {
#pragma unroll
                for (int t = 0; t < 4; t++) {
                    int e = tid + 256 * t; int j = e >> 3, c8 = (e & 7) * 8;
                    *(bf16x8*)&upool[j * 72 + c8] = *(const bf16x8*)&ckb[((long)(b * 128 + j)) * 1024 + h * 64 + c8];
                }
#pragma unroll
                for (int t = 0; t < 4; t++) {
                    int e = tid + 256 * t; int d = e >> 4, j8 = (e & 15) * 8;
                    *(bf16x8*)&vt[d][j8] = *(const bf16x8*)&cvT[((long)z * 64 + d) * 128 + j8];
                }
            }
            __syncthreads();

#pragma unroll
            for (int i = 0; i < 2; i++)
#pragma unroll
                for (int j = 0; j < 8; j++) sacc[i][j] = (f32x4){0.f, 0.f, 0.f, 0.f};
#pragma unroll
            for (int s = 0; s < 2; s++) {
                bf16x8 af[2], bfv[8];
#pragma unroll
                for (int i = 0; i < 2; i++)
                    af[i] = *(const bf16x8*)&qs[wid * 32 + i * 16 + fr][s * 32 + fq * 8];
#pragma unroll
                for (int j = 0; j < 8; j++)
                    bfv[j] = *(const bf16x8*)&upool[(j * 16 + fr) * 72 + s * 32 + fq * 8];
#pragma unroll
                for (int i = 0; i < 2; i++)
#pragma unroll
                    for (int j = 0; j < 8; j++)
                        sacc[i][j] = __builtin_amdgcn_mfma_f32_16x16x32_bf16(af[i], bfv[j], sacc[i][j], 0, 0, 0);
            }
            __syncthreads();

#pragma unroll
            for (int i = 0; i < 2; i++) {
#pragma unroll
                for (int g = 0; g < 4; g++) {
                    float mx = -3.4e38f;
#pragma unroll
                    for (int j = 0; j < 8; j++) mx = fmaxf(mx, sacc[i][j][g]);
                    mx *= 0.125f;
#pragma unroll
                    for (int msk = 1; msk <= 8; msk <<= 1) mx = fmaxf(mx, __shfl_xor(mx, msk, 64));
                    float mnew = fmaxf(mrow[i][g], mx);
                    float alpha = __expf(mrow[i][g] - mnew);
                    mrow[i][g] = mnew;
                    float sum = 0.f;
                    int prow = (wid * 32 + i * 16 + fq * 4 + g) * 136;
#pragma unroll
                    for (int j = 0; j < 8; j++) {
                        float p = __expf(sacc[i][j][g] * 0.125f - mnew);
                        sum += p;
                        upool[prow + j * 16 + fr] = (bf16)p;
                    }
#pragma unroll
                    for (int msk = 1; msk <= 8; msk <<= 1) sum += __shfl_xor(sum, msk, 16);
                    lrow[i][g] = lrow[i][g] * alpha + sum;
#pragma unroll
                    for (int jd = 0; jd < 4; jd++) oaccv[i][jd][g] *= alpha;
                }
            }
            __syncthreads();

#pragma unroll
            for (int s2 = 0; s2 < 4; s2++) {
                bf16x8 pa[2], vb[4];
#pragma unroll
                for (int i = 0; i < 2; i++)
                    pa[i] = *(const bf16x8*)&upool[(wid * 32 + i * 16 + fr) * 136 + s2 * 32 + fq * 8];
#pragma unroll
                for (int jd = 0; jd < 4; jd++)
                    vb[jd] = *(const bf16x8*)&vt[jd * 16 + fr][s2 * 32 + fq * 8];
#pragma unroll
                for (int i = 0; i < 2; i++)
#pragma unroll
                    for (int jd = 0; jd < 4; jd++)
                        oaccv[i][jd] = __builtin_amdgcn_mfma_f32_16x16x32_bf16(pa[i], vb[jd], oaccv[i][jd], 0, 0, 0);
            }
        }

        if (pass == 0) {
#pragma unroll
            for (int i = 0; i < 2; i++)
#pragma unroll
                for (int jd = 0; jd < 4; jd++)
#pragma unroll
                    for (int g = 0; g < 4; g++)
                        o1[i][jd][g] = oaccv[i][jd][g] / lrow[i][g];
        } else {
#pragma unroll
            for (int i = 0; i < 2; i++)
#pragma unroll
                for (int jd = 0; jd < 4; jd++)
#pragma unroll
                    for (int g = 0; g < 4; g++) {
                        float dd = o1[i][jd][g] - oaccv[i][jd][g] / lrow[i][g];
                        local += dd * dd;
                    }
        }
    }

#pragma unroll
    for (int off = 32; off; off >>= 1) local += __shfl_xor(local, off, 64);
    if (lane == 0) wred[wid] = local;
    __syncthreads();
    if (tid == 0)
        partials[(long)blockIdx.y * 4 + blockIdx.x] = wred[0] + wred[1] + wred[2] + wred[3];
}

__global__ __launch_bounds__(256)
void aux_reduce_kernel(const float* __restrict__ partials, float* __restrict__ out)
{
    int tid = threadIdx.x;
    __shared__ float wred[4];
    float s = 0.f;
    for (int i = tid; i < 512; i += 256) s += partials[i];
#pragma unroll
    for (int off = 32; off; off >>= 1) s += __shfl_xor(s, off, 64);
    if ((tid & 63) == 0) wred[tid >> 6] = s;
    __syncthreads();
    if (tid == 0) out[0] = (wred[0] + wred[1] + wred[2] + wred[3]) * (1.0f / 4194304.0f);
}

__global__ __launch_bounds__(256)
void copy_kernel(float* __restrict__ dst, const float* __restrict__ src, int n4)
{
    int i = blockIdx.x * 256 + threadIdx.x;
    int stride = gridDim.x * 256;
    for (; i < n4; i += stride) {
        f32x4 v = reinterpret_cast<const f32x4*>(src)[i];
        __builtin_nontemporal_store(v, &reinterpret_cast<f32x4*>(dst)[i]);
    }
}

extern "C" void kernel_launch(void* const* d_in, const int* in_sizes, int n_in,
                              void* d_out, int out_size, void* d_ws, size_t ws_size,
                              hipStream_t stream)
{
    const float* x      = (const float*)d_in[0];
    const float* mem    = (const float*)d_in[1];
    const float* cmem   = (const float*)d_in[2];
    const float* pe     = (const float*)d_in[3];
    const float* Wq     = (const float*)d_in[4];
    const float* Wkv    = (const float*)d_in[5];
    const float* Wout   = (const float*)d_in[6];
    const float* bout   = (const float*)d_in[7];
    const float* conv_w = (const float*)d_in[8];
    const float* conv_b = (const float*)d_in[9];

    float* out_logits  = (float*)d_out;                 // 8*512*1024
    float* out_newmem  = out_logits + 4194304;          // 8*512*1024
    float* out_newcmem = out_newmem + 4194304;          // 8*128*1024
    float* out_aux     = out_newcmem + 1048576;         // 1
    float* out_weights = out_aux + 1;                   // 8*16*512*1152

    float* ws       = (float*)d_ws;
    float* partials = ws;                    // 4096 f
    bf16* bws     = (bf16*)(partials + 4096);
    bf16* WqTb    = bws;                     // 1,048,576
    bf16* WkvTb   = WqTb + 1048576;          // 2,097,152
    bf16* WoutTb  = WkvTb + 2097152;         // 1,048,576
    bf16* convwTb = WoutTb + 1048576;        // 4,194,304
    bf16* vTb     = convwTb + 4194304;       // 9,437,184
    bf16* cvT     = vTb + 9437184;           // 1,048,576
    bf16* qb      = cvT + 1048576;           // 4,194,304
    bf16* kb      = qb + 4194304;            // 9,437,184
    bf16* ckb     = kb + 9437184;            // 1,048,576
    bf16* peb     = ckb + 1048576;           // 1,179,648
    bf16* xb      = peb + 1179648;           // 4,194,304
    bf16* memb    = xb + 4194304;            // 4,194,304
    bf16* cmemb   = memb + 4194304;          // 1,048,576
    bf16* ncmemb  = cmemb + 1048576;         // 1,048,576
    bf16* oatb    = ncmemb + 1048576;        // 4,194,304

    dim3 blk(256);

    transpose_cast<<<dim3(32, 32), blk, 0, stream>>>(Wq, WqTb, 1024, 1024);
    transpose_cast<<<dim3(64, 32), blk, 0, stream>>>(Wkv, WkvTb, 1024, 2048);
    transpose_cast<<<dim3(32, 32), blk, 0, stream>>>(Wout, WoutTb, 1024, 1024);
    convw_cast<<<dim3(1024), blk, 0, stream>>>(conv_w, convwTb);
    cast_f2b<<<dim3(1152), blk, 0, stream>>>(pe, peb, 294912);
    cast_f2b<<<dim3(2048), blk, 0, stream>>>(x, xb, 1048576);
    cast_f2b<<<dim3(2048), blk, 0, stream>>>(mem, memb, 1048576);
    cast_f2b<<<dim3(1024), blk, 0, stream>>>(cmem, cmemb, 262144);

    // qb = bf16(x @ Wq)
    mfma_gemm<0, 4><<<dim3(8, 32, 1), blk, 0, stream>>>(
        xb, WqTb, nullptr, qb, nullptr, 1024, 1024, 1024, 1024, 1024,
        nullptr, 0, nullptr, nullptr, nullptr);

    // kb/vTb = bf16(concat(cmem,mem,x) @ Wkv)
    mfma_gemm<1, 5><<<dim3(16, 72, 1), blk, 0, stream>>>(
        nullptr, WkvTb, nullptr, kb, vTb, 2048, 1024, 1024, 1024, 2048,
        nullptr, 1152, cmemb, memb, xb);

    // new_cmem = mem[1024x4096] @ convwT + conv_b  (fp32 output + bf16 ncmemb)
    mfma_gemm<0, 7><<<dim3(8, 8, 1), blk, 0, stream>>>(
        memb, convwTb, out_newcmem, ncmemb, nullptr, 1024, 4096, 4096, 4096, 1024,
        conv_b, 0, nullptr, nullptr, nullptr);

    // ckb/cvT = bf16(new_cmem @ Wkv)
    mfma_gemm<0, 5><<<dim3(16, 8, 1), blk, 0, stream>>>(
        ncmemb, WkvTb, nullptr, ckb, cvT, 2048, 1024, 1024, 1024, 2048,
        nullptr, 128, nullptr, nullptr, nullptr);

    // fused attention with XCD-chunked swizzle (8 waves, role-split epilogue)
    attn_fused16<<<dim3(4096), dim3(512), 0, stream>>>(qb, kb, peb, vTb, out_weights, oatb);

    // logits = oat @ Wout + bout (non-temporal output)
    mfma_gemm<0, 6><<<dim3(8, 32, 1), blk, 0, stream>>>(
        oatb, WoutTb, out_logits, nullptr, nullptr, 1024, 1024, 1024, 1024, 1024,
        bout, 0, nullptr, nullptr, nullptr);

    // new_mem = x (non-temporal)
    copy_kernel<<<dim3(4096), blk, 0, stream>>>(out_newmem, x, 1048576);

    // aux loss
    aux_mfma_kernel<<<dim3(4, 128), blk, 0, stream>>>(qb, kb, ckb, vTb, cvT, partials);
    aux_reduce_kernel<<<dim3(1), blk, 0, stream>>>(partials, out_aux);
}

// Round 15
// 678.552 us; speedup vs baseline: 1.0779x; 1.0585x over previous
//
#include <hip/hip_runtime.h>
#include <cstdint>

// HEADS=16, DIM=1024, SEQ=512, MEM=512, CMEM=128, RATIO=4, DIM_H=64, b=8, kv_len=1152

typedef __bf16 bf16;
typedef __bf16 bf16x2 __attribute__((ext_vector_type(2)));
typedef __bf16 bf16x4 __attribute__((ext_vector_type(4)));
typedef __bf16 bf16x8 __attribute__((ext_vector_type(8)));
typedef float  f32x2  __attribute__((ext_vector_type(2)));
typedef float  f32x4  __attribute__((ext_vector_type(4)));

// ---------------------------------------------------------------------------
// MFMA GEMM: C[M,N] = A[M,K] @ B[K,N], tile 128x128, BK=32, 4 waves.
// ---------------------------------------------------------------------------
template<int AMODE, int EPI>
__global__ __launch_bounds__(256)
void mfma_gemm(const bf16* __restrict__ A, const bf16* __restrict__ B2,
               float* __restrict__ C, bf16* __restrict__ outB, bf16* __restrict__ vT,
               int N, int K, int lda, int ldbt, int ldc,
               const float* __restrict__ bias, int vrows,
               const bf16* __restrict__ gcmem, const bf16* __restrict__ gmem,
               const bf16* __restrict__ gx)
{
    int row0 = blockIdx.y * 128, col0 = blockIdx.x * 128;
    int tid = threadIdx.x;

    __shared__ bf16 As[128][72];
    __shared__ bf16 Bs[128][72];

    int rn_ = tid >> 2;           // 0..63
    int c8  = (tid & 3) * 8;      // k-chunk (bf16)

    const bf16* aptr[2];
#pragma unroll
    for (int jj = 0; jj < 2; jj++) {
        int gr = row0 + rn_ + 64 * jj;
        if (AMODE == 0) {
            aptr[jj] = A + (long)gr * lda;
        } else {
            int bb = gr / 1152, rr = gr - bb * 1152;
            aptr[jj] = (rr < 128) ? (gcmem + ((long)bb * 128 + rr) * 1024)
                     : (rr < 640) ? (gmem + ((long)bb * 512 + (rr - 128)) * 1024)
                                  : (gx   + ((long)bb * 512 + (rr - 640)) * 1024);
        }
    }
    const bf16* bptr[2];
#pragma unroll
    for (int jj = 0; jj < 2; jj++) {
        int gc = col0 + rn_ + 64 * jj;
        bptr[jj] = (gc < N) ? (B2 + (long)gc * ldbt + c8) : nullptr;
    }

    int lane = tid & 63, wid = tid >> 6;
    int wr = wid >> 1, wc = wid & 1;
    int fr = lane & 15, fq = lane >> 4;

    f32x4 acc[4][4];
#pragma unroll
    for (int i = 0; i < 4; i++)
#pragma unroll
        for (int j = 0; j < 4; j++) acc[i][j] = (f32x4){0.f, 0.f, 0.f, 0.f};

    for (int k0 = 0; k0 < K; k0 += 32) {
#pragma unroll
        for (int jj = 0; jj < 2; jj++) {
            bf16x8 v = *(const bf16x8*)(aptr[jj] + k0 + c8);
            *(bf16x8*)&As[rn_ + 64 * jj][c8] = v;
        }
#pragma unroll
        for (int jj = 0; jj < 2; jj++) {
            bf16x8 v = {};
            if (bptr[jj]) v = *(const bf16x8*)(bptr[jj] + k0);
            *(bf16x8*)&Bs[rn_ + 64 * jj][c8] = v;
        }
        __syncthreads();

        bf16x8 af[4], bfv[4];
#pragma unroll
        for (int i = 0; i < 4; i++)
            af[i] = *(const bf16x8*)&As[wr * 64 + i * 16 + fr][fq * 8];
#pragma unroll
        for (int j = 0; j < 4; j++)
            bfv[j] = *(const bf16x8*)&Bs[wc * 64 + j * 16 + fr][fq * 8];
#pragma unroll
        for (int i = 0; i < 4; i++)
#pragma unroll
            for (int j = 0; j < 4; j++)
                acc[i][j] = __builtin_amdgcn_mfma_f32_16x16x32_bf16(af[i], bfv[j], acc[i][j], 0, 0, 0);
        __syncthreads();
    }

#pragma unroll
    for (int i = 0; i < 4; i++) {
#pragma unroll
        for (int j = 0; j < 4; j++) {
#pragma unroll
            for (int g = 0; g < 4; g++) {
                int r = row0 + wr * 64 + i * 16 + fq * 4 + g;
                int c = col0 + wc * 64 + j * 16 + fr;
                float v = acc[i][j][g];
                if (EPI == 0) {
                    if (c < N) {
                        if (bias) v += bias[c];
                        C[(long)r * ldc + c] = v;
                    }
                } else if (EPI == 6) {
                    if (c < N) {
                        if (bias) v += bias[c];
                        __builtin_nontemporal_store(v, &C[(long)r * ldc + c]);
                    }
                } else if (EPI == 7) {
                    if (c < N) {
                        if (bias) v += bias[c];
                        C[(long)r * ldc + c] = v;
                        outB[(long)r * 1024 + c] = (bf16)v;
                    }
                } else if (EPI == 4) {
                    if (c < N) outB[(long)r * ldc + c] = (bf16)v;
                } else { // EPI == 5
                    if (c < 1024) {
                        outB[(long)r * 1024 + c] = (bf16)v;
                    } else {
                        int d = c - 1024; int hh = d >> 6; d &= 63;
                        int bb = r / vrows; int j2 = r - bb * vrows;
                        vT[(((long)(bb * 16 + hh)) * 64 + d) * vrows + j2] = (bf16)v;
                    }
                }
            }
        }
    }
}

// fp32 [R][C] -> bf16 [C][R]
__global__ __launch_bounds__(256)
void transpose_cast(const float* __restrict__ in, bf16* __restrict__ out, int R, int C)
{
    __shared__ float t[32][33];
    int c0 = blockIdx.x * 32, r0 = blockIdx.y * 32;
    int tx = threadIdx.x & 31, ty = threadIdx.x >> 5;
#pragma unroll
    for (int i = 0; i < 32; i += 8)
        t[ty + i][tx] = in[(long)(r0 + ty + i) * C + c0 + tx];
    __syncthreads();
#pragma unroll
    for (int i = 0; i < 32; i += 8)
        out[(long)(c0 + ty + i) * R + r0 + tx] = (bf16)t[tx][ty + i];
}

// conv_w [o][i][r] -> bf16 [o][r*1024+i], LDS-staged (coalesced global read)
__global__ __launch_bounds__(256)
void convw_cast(const float* __restrict__ cw, bf16* __restrict__ out)
{
    long o = blockIdx.x;
    const float* src = cw + o * 4096;
    bf16* dst = out + o * 4096;
    __shared__ float t[4096];
#pragma unroll
    for (int k = 0; k < 4; k++)
        *(f32x4*)&t[(threadIdx.x + k * 256) * 4] = *(const f32x4*)&src[(threadIdx.x + k * 256) * 4];
    __syncthreads();
#pragma unroll
    for (int k = 0; k < 8; k++) {
        int d2 = 2 * (threadIdx.x + k * 256);
        int pi = ((d2 & 1023) << 2) | (d2 >> 10);
        bf16x2 h = { (bf16)t[pi], (bf16)t[pi + 4] };
        *(bf16x2*)&dst[d2] = h;
    }
}

// merged segmented fp32 -> bf16 cast: pe | x | mem | cmem in one launch
__global__ __launch_bounds__(256)
void cast_f2b_multi(const float* __restrict__ s0, bf16* __restrict__ d0, int n0,
                    const float* __restrict__ s1, bf16* __restrict__ d1, int n1,
                    const float* __restrict__ s2, bf16* __restrict__ d2, int n2,
                    const float* __restrict__ s3, bf16* __restrict__ d3, int n3)
{
    int i = blockIdx.x * 256 + threadIdx.x;
    int stride = gridDim.x * 256;
    int ntot = n0 + n1 + n2 + n3;
    for (; i < ntot; i += stride) {
        const float* src; bf16* dst; int k = i;
        if (k < n0) { src = s0; dst = d0; }
        else if ((k -= n0) < n1) { src = s1; dst = d1; }
        else if ((k -= n1) < n2) { src = s2; dst = d2; }
        else { k -= n2; src = s3; dst = d3; }
        float4 f = reinterpret_cast<const float4*>(src)[k];
        bf16x4 h = { (bf16)f.x, (bf16)f.y, (bf16)f.z, (bf16)f.w };
        reinterpret_cast<bf16x4*>(dst)[k] = h;
    }
}

// ---------------------------------------------------------------------------
// Fused attention (round-10 best): 16 q-rows/block, 4 waves, XCD swizzle,
// S in LDS, vectorized softmax, NT tail weights write.
// ---------------------------------------------------------------------------
#define SSTR 1164

__global__ __launch_bounds__(256)
void attn_fused16(const bf16* __restrict__ qb, const bf16* __restrict__ kb,
                  const bf16* __restrict__ peb, const bf16* __restrict__ vTb,
                  float* __restrict__ weights, bf16* __restrict__ oatb)
{
    int bid = blockIdx.x;
    int w = (bid & 7) * 512 + (bid >> 3);
    int z = w >> 5;
    int b = z >> 4, h = z & 15;
    int r0 = (w & 31) * 16;
    int tid = threadIdx.x;
    int lane = tid & 63, wid = tid >> 6;
    int fr = lane & 15, fq = lane >> 4;

    __shared__ bf16 S[16 * SSTR];

    bf16x8 afr[2];
#pragma unroll
    for (int ks = 0; ks < 2; ks++)
        afr[ks] = *(const bf16x8*)&qb[((long)(b * 512 + r0 + fr)) * 1024 + h * 64 + ks * 32 + fq * 8];

#pragma unroll 3
    for (int ch = 0; ch < 9; ch++) {
        int c0 = ch * 128;
        int jb0 = c0 + 496 - r0 + 32 * wid;

        f32x4 p[3];
#pragma unroll
        for (int ct = 0; ct < 3; ct++) {
            f32x4 a = (f32x4){0.f, 0.f, 0.f, 0.f};
            int j = jb0 + ct * 16 + fr;
            bool ok = (j < 1152);
#pragma unroll
            for (int ks = 0; ks < 2; ks++) {
                bf16x8 bv = {};
                if (ok) bv = *(const bf16x8*)&peb[((long)(h * 1152 + j)) * 64 + ks * 32 + fq * 8];
                a = __builtin_amdgcn_mfma_f32_16x16x32_bf16(afr[ks], bv, a, 0, 0, 0);
            }
            p[ct] = a;
        }

#pragma unroll
        for (int tt = 0; tt < 2; tt++) {
            int cc = 32 * wid + 16 * tt + fr;
            f32x4 a = (f32x4){0.f, 0.f, 0.f, 0.f};
            long krow = (long)(b * 1152 + c0 + cc);
#pragma unroll
            for (int ks = 0; ks < 2; ks++) {
                bf16x8 bv = *(const bf16x8*)&kb[krow * 1024 + h * 64 + ks * 32 + fq * 8];
                a = __builtin_amdgcn_mfma_f32_16x16x32_bf16(afr[ks], bv, a, 0, 0, 0);
            }
#pragma unroll
            for (int g = 0; g < 4; g++) {
                int rr = fq * 4 + g;
                int uu = fr + 15 - rr;
                int src = (uu & 15) | (fq << 4);
                float s0 = __shfl(p[tt][g], src, 64);
                float s1 = __shfl(p[tt + 1][g], src, 64);
                float pv = (uu < 16) ? s0 : s1;
                S[rr * SSTR + c0 + cc] = (bf16)(0.125f * (a[g] + pv));
            }
        }
    }
    __syncthreads();

    for (int rw = 0; rw < 4; rw++) {
        int row = wid * 4 + rw;
        bf16* Srow = &S[row * SSTR];
        bf16x8 v0 = *(const bf16x8*)&Srow[lane * 8];
        bf16x8 v1 = *(const bf16x8*)&Srow[512 + lane * 8];
        bf16x2 v2 = *(const bf16x2*)&Srow[1024 + lane * 2];
        float e[18];
#pragma unroll
        for (int j = 0; j < 8; j++) { e[j] = (float)v0[j]; e[8 + j] = (float)v1[j]; }
        e[16] = (float)v2[0]; e[17] = (float)v2[1];

        float m = e[0];
#pragma unroll
        for (int k = 1; k < 18; k++) m = fmaxf(m, e[k]);
#pragma unroll
        for (int off = 32; off; off >>= 1) m = fmaxf(m, __shfl_xor(m, off, 64));
        float sm = 0.f;
#pragma unroll
        for (int k = 0; k < 18; k++) { e[k] = __expf(e[k] - m); sm += e[k]; }
#pragma unroll
        for (int off = 32; off; off >>= 1) sm += __shfl_xor(sm, off, 64);
        float inv = 1.f / sm;

        bf16x8 w0, w1; bf16x2 w2;
#pragma unroll
        for (int j = 0; j < 8; j++) { w0[j] = (bf16)(e[j] * inv); w1[j] = (bf16)(e[8 + j] * inv); }
        w2[0] = (bf16)(e[16] * inv); w2[1] = (bf16)(e[17] * inv);
        *(bf16x8*)&Srow[lane * 8] = w0;
        *(bf16x8*)&Srow[512 + lane * 8] = w1;
        *(bf16x2*)&Srow[1024 + lane * 2] = w2;
    }
    __syncthreads();

    f32x4 oacc = (f32x4){0.f, 0.f, 0.f, 0.f};
    int dt = wid;
    for (int ch = 0; ch < 9; ch++) {
        int c0 = ch * 128;
#pragma unroll
        for (int ks = 0; ks < 4; ks++) {
            bf16x8 pa = *(const bf16x8*)&S[fr * SSTR + c0 + ks * 32 + fq * 8];
            bf16x8 vb = *(const bf16x8*)&vTb[((long)z * 64 + dt * 16 + fr) * 1152 + c0 + ks * 32 + fq * 8];
            oacc = __builtin_amdgcn_mfma_f32_16x16x32_bf16(pa, vb, oacc, 0, 0, 0);
        }
    }
#pragma unroll
    for (int g = 0; g < 4; g++)
        oatb[((long)(b * 512 + r0 + fq * 4 + g)) * 1024 + h * 64 + dt * 16 + fr] = (bf16)oacc[g];

    for (int rw = 0; rw < 4; rw++) {
        int row = wid * 4 + rw;
        const bf16* Srow = &S[row * SSTR];
        long wbase = ((long)z * 512 + r0 + row) * 1152;
        bf16x8 v0 = *(const bf16x8*)&Srow[lane * 8];
        bf16x8 v1 = *(const bf16x8*)&Srow[512 + lane * 8];
        bf16x2 v2 = *(const bf16x2*)&Srow[1024 + lane * 2];
        f32x4 a0 = { (float)v0[0], (float)v0[1], (float)v0[2], (float)v0[3] };
        f32x4 a1 = { (float)v0[4], (float)v0[5], (float)v0[6], (float)v0[7] };
        f32x4 b0 = { (float)v1[0], (float)v1[1], (float)v1[2], (float)v1[3] };
        f32x4 b1 = { (float)v1[4], (float)v1[5], (float)v1[6], (float)v1[7] };
        f32x2 c0 = { (float)v2[0], (float)v2[1] };
        __builtin_nontemporal_store(a0, (f32x4*)&weights[wbase + lane * 8]);
        __builtin_nontemporal_store(a1, (f32x4*)&weights[wbase + lane * 8 + 4]);
        __builtin_nontemporal_store(b0, (f32x4*)&weights[wbase + 512 + lane * 8]);
        __builtin_nontemporal_store(b1, (f32x4*)&weights[wbase + 512 + lane * 8 + 4]);
        __builtin_nontemporal_store(c0, (f32x2*)&weights[wbase + 1024 + lane * 2]);
    }
}

// ---------------------------------------------------------------------------
// Fused MFMA aux loss (round-10 version, verified)
// ---------------------------------------------------------------------------
__global__ __launch_bounds__(256)
void aux_mfma_kernel(const bf16* __restrict__ qb, const bf16* __restrict__ kb,
                     const bf16* __restrict__ ckb,
                     const bf16* __restrict__ vTb, const bf16* __restrict__ cvT,
                     float* __restrict__ partials)
{
    int z = blockIdx.y;
    int b = z >> 4, h = z & 15;
    int r0 = blockIdx.x * 128;
    int tid = threadIdx.x;
    int lane = tid & 63, wid = tid >> 6;
    int fr = lane & 15, fq = lane >> 4;

    __shared__ bf16 qs[128][72];
    __shared__ bf16 upool[128 * 136];
    __shared__ bf16 vt[64][136];
    __shared__ float wred[4];

#pragma unroll
    for (int t = 0; t < 4; t++) {
        int e = tid + 256 * t; int rr = e >> 3, c8 = (e & 7) * 8;
        *(bf16x8*)&qs[rr][c8] = *(const bf16x8*)&qb[((long)(b * 512 + r0 + rr)) * 1024 + h * 64 + c8];
    }

    float o1[2][4][4];
    f32x4 oaccv[2][4];
    float mrow[2][4], lrow[2][4];
    f32x4 sacc[2][8];
    float local = 0.f;

    for (int pass = 0; pass < 2; pass++) {
#pragma unroll
        for (int i = 0; i < 2; i++)
#pragma unroll
            for (int g = 0; g < 4; g++) { mrow[i][g] = -3.4e38f; lrow[i][g] = 0.f; }
#pragma unroll
        for (int i = 0; i < 2; i++)
#pragma unroll
            for (int jd = 0; jd < 4; jd++) oaccv[i][jd] = (f32x4){0.f, 0.f, 0.f, 0.f};

        int nchunk = pass ? 1 : 4;
        for (int jt = 0; jt < nchunk; jt++) {
            __syncthreads();
            if (pass == 0) {
                long base = (long)(b * 1152 + 128 + jt * 128);
#pragma unroll
                for (int t = 0; t < 4; t++) {
                    int e = tid + 256 * t; int j = e >> 3, c8 = (e & 7) * 8;
                    *(bf16x8*)&upool[j * 72 + c8] = *(const bf16x8*)&kb[(base + j) * 1024 + h * 64 + c8];
                }
#pragma unroll
                for (int t = 0; t < 4; t++) {
                    int e = tid + 256 * t; int d = e >> 4, j8 = (e & 15) * 8;
                    *(bf16x8*)&vt[d][j8] =
                        *(const bf16x8*)&vTb[((long)z * 64 + d) * 1152 + 128 + jt * 128 + j8];
                }
            } else {
#pragma unroll
                for (int t = 0; t < 4; t++) {
                    int e = tid + 256 * t; int j = e >> 3, c8 = (e & 7) * 8;
                    *(bf16x8*)&upool[j * 72 + c8] = *(const bf16x8*)&ckb[((long)(b * 128 + j)) * 1024 + h * 64 + c8];
                }
#pragma unroll
                for (int t = 0; t < 4; t++) {
                    int e = tid + 256 * t; int d = e >> 4, j8 = (e & 15) * 8;
                    *(bf16x8*)&vt[d][j8] = *(const bf16x8*)&cvT[((long)z * 64 + d) * 128 + j8];
                }
            }
            __syncthreads();

#pragma unroll
            for (int i = 0; i < 2; i++)
#pragma unroll
                for (int j = 0; j < 8; j++) sacc[i][j] = (f32x4){0.f, 0.f, 0.f, 0.f};
#pragma unroll
            for (int s = 0; s < 2; s++) {
                bf16x8 af[2], bfv[8];
#pragma unroll
                for (int i = 0; i < 2; i++)
                    af[i] = *(const bf16x8*)&qs[wid * 32 + i * 16 + fr][s * 32 + fq * 8];
#pragma unroll
                for (int j = 0; j < 8; j++)
                    bfv[j] = *(const bf16x8*)&upool[(j * 16 + fr) * 72 + s * 32 + fq * 8];
#pragma unroll
                for (int i = 0; i < 2; i++)
#pragma unroll
                    for (int j = 0; j < 8; j++)
                        sacc[i][j] = __builtin_amdgcn_mfma_f32_16x16x32_bf16(af[i], bfv[j], sacc[i][j], 0, 0, 0);
            }
            __syncthreads();

#pragma unroll
            for (int i = 0; i < 2; i++) {
#pragma unroll
                for (int g = 0; g < 4; g++) {
                    float mx = -3.4e38f;
#pragma unroll
                    for (int j = 0; j < 8; j++) mx = fmaxf(mx, sacc[i][j][g]);
                    mx *= 0.125f;
#pragma unroll
                    for (int msk = 1; msk <= 8; msk <<= 1) mx = fmaxf(mx, __shfl_xor(mx, msk, 64));
                    float mnew = fmaxf(mrow[i][g], mx);
                    float alpha = __expf(mrow[i][g] - mnew);
                    mrow[i][g] = mnew;
                    float sum = 0.f;
                    int prow = (wid * 32 + i * 16 + fq * 4 + g) * 136;
#pragma unroll
                    for (int j = 0; j < 8; j++) {
                        float p = __expf(sacc[i][j][g] * 0.125f - mnew);
                        sum += p;
                        upool[prow + j * 16 + fr] = (bf16)p;
                    }
#pragma unroll
                    for (int msk = 1; msk <= 8; msk <<= 1) sum += __shfl_xor(sum, msk, 16);
                    lrow[i][g] = lrow[i][g] * alpha + sum;
#pragma unroll
                    for (int jd = 0; jd < 4; jd++) oaccv[i][jd][g] *= alpha;
                }
            }
            __syncthreads();

#pragma unroll
            for (int s2 = 0; s2 < 4; s2++) {
                bf16x8 pa[2], vb[4];
#pragma unroll
                for (int i = 0; i < 2; i++)
                    pa[i] = *(const bf16x8*)&upool[(wid * 32 + i * 16 + fr) * 136 + s2 * 32 + fq * 8];
#pragma unroll
                for (int jd = 0; jd < 4; jd++)
                    vb[jd] = *(const bf16x8*)&vt[jd * 16 + fr][s2 * 32 + fq * 8];
#pragma unroll
                for (int i = 0; i < 2; i++)
#pragma unroll
                    for (int jd = 0; jd < 4; jd++)
                        oaccv[i][jd] = __builtin_amdgcn_mfma_f32_16x16x32_bf16(pa[i], vb[jd], oaccv[i][jd], 0, 0, 0);
            }
        }

        if (pass == 0) {
#pragma unroll
            for (int i = 0; i < 2; i++)
#pragma unroll
                for (int jd = 0; jd < 4; jd++)
#pragma unroll
                    for (int g = 0; g < 4; g++)
                        o1[i][jd][g] = oaccv[i][jd][g] / lrow[i][g];
        } else {
#pragma unroll
            for (int i = 0; i < 2; i++)
#pragma unroll
                for (int jd = 0; jd < 4; jd++)
#pragma unroll
                    for (int g = 0; g < 4; g++) {
                        float dd = o1[i][jd][g] - oaccv[i][jd][g] / lrow[i][g];
                        local += dd * dd;
                    }
        }
    }

#pragma unroll
    for (int off = 32; off; off >>= 1) local += __shfl_xor(local, off, 64);
    if (lane == 0) wred[wid] = local;
    __syncthreads();
    if (tid == 0)
        partials[(long)blockIdx.y * 4 + blockIdx.x] = wred[0] + wred[1] + wred[2] + wred[3];
}

__global__ __launch_bounds__(256)
void aux_reduce_kernel(const float* __restrict__ partials, float* __restrict__ out)
{
    int tid = threadIdx.x;
    __shared__ float wred[4];
    float s = 0.f;
    for (int i = tid; i < 512; i += 256) s += partials[i];
#pragma unroll
    for (int off = 32; off; off >>= 1) s += __shfl_xor(s, off, 64);
    if ((tid & 63) == 0) wred[tid >> 6] = s;
    __syncthreads();
    if (tid == 0) out[0] = (wred[0] + wred[1] + wred[2] + wred[3]) * (1.0f / 4194304.0f);
}

__global__ __launch_bounds__(256)
void copy_kernel(float* __restrict__ dst, const float* __restrict__ src, int n4)
{
    int i = blockIdx.x * 256 + threadIdx.x;
    int stride = gridDim.x * 256;
    for (; i < n4; i += stride) {
        f32x4 v = reinterpret_cast<const f32x4*>(src)[i];
        __builtin_nontemporal_store(v, &reinterpret_cast<f32x4*>(dst)[i]);
    }
}

extern "C" void kernel_launch(void* const* d_in, const int* in_sizes, int n_in,
                              void* d_out, int out_size, void* d_ws, size_t ws_size,
                              hipStream_t stream)
{
    const float* x      = (const float*)d_in[0];
    const float* mem    = (const float*)d_in[1];
    const float* cmem   = (const float*)d_in[2];
    const float* pe     = (const float*)d_in[3];
    const float* Wq     = (const float*)d_in[4];
    const float* Wkv    = (const float*)d_in[5];
    const float* Wout   = (const float*)d_in[6];
    const float* bout   = (const float*)d_in[7];
    const float* conv_w = (const float*)d_in[8];
    const float* conv_b = (const float*)d_in[9];

    float* out_logits  = (float*)d_out;                 // 8*512*1024
    float* out_newmem  = out_logits + 4194304;          // 8*512*1024
    float* out_newcmem = out_newmem + 4194304;          // 8*128*1024
    float* out_aux     = out_newcmem + 1048576;         // 1
    float* out_weights = out_aux + 1;                   // 8*16*512*1152

    float* ws       = (float*)d_ws;
    float* partials = ws;                    // 4096 f
    bf16* bws     = (bf16*)(partials + 4096);
    bf16* WqTb    = bws;                     // 1,048,576
    bf16* WkvTb   = WqTb + 1048576;          // 2,097,152
    bf16* WoutTb  = WkvTb + 2097152;         // 1,048,576
    bf16* convwTb = WoutTb + 1048576;        // 4,194,304
    bf16* vTb     = convwTb + 4194304;       // 9,437,184
    bf16* cvT     = vTb + 9437184;           // 1,048,576
    bf16* qb      = cvT + 1048576;           // 4,194,304
    bf16* kb      = qb + 4194304;            // 9,437,184
    bf16* ckb     = kb + 9437184;            // 1,048,576
    bf16* peb     = ckb + 1048576;           // 1,179,648
    bf16* xb      = peb + 1179648;           // 4,194,304
    bf16* memb    = xb + 4194304;            // 4,194,304
    bf16* cmemb   = memb + 4194304;          // 1,048,576
    bf16* ncmemb  = cmemb + 1048576;         // 1,048,576
    bf16* oatb    = ncmemb + 1048576;        // 4,194,304

    dim3 blk(256);

    transpose_cast<<<dim3(32, 32), blk, 0, stream>>>(Wq, WqTb, 1024, 1024);
    transpose_cast<<<dim3(64, 32), blk, 0, stream>>>(Wkv, WkvTb, 1024, 2048);
    transpose_cast<<<dim3(32, 32), blk, 0, stream>>>(Wout, WoutTb, 1024, 1024);
    convw_cast<<<dim3(1024), blk, 0, stream>>>(conv_w, convwTb);
    // merged input casts: pe | x | mem | cmem
    cast_f2b_multi<<<dim3(2048), blk, 0, stream>>>(
        pe, peb, 294912, x, xb, 1048576, mem, memb, 1048576, cmem, cmemb, 262144);

    // qb = bf16(x @ Wq)
    mfma_gemm<0, 4><<<dim3(8, 32, 1), blk, 0, stream>>>(
        xb, WqTb, nullptr, qb, nullptr, 1024, 1024, 1024, 1024, 1024,
        nullptr, 0, nullptr, nullptr, nullptr);

    // kb/vTb = bf16(concat(cmem,mem,x) @ Wkv)
    mfma_gemm<1, 5><<<dim3(16, 72, 1), blk, 0, stream>>>(
        nullptr, WkvTb, nullptr, kb, vTb, 2048, 1024, 1024, 1024, 2048,
        nullptr, 1152, cmemb, memb, xb);

    // new_cmem = mem[1024x4096] @ convwT + conv_b  (fp32 output + bf16 ncmemb)
    mfma_gemm<0, 7><<<dim3(8, 8, 1), blk, 0, stream>>>(
        memb, convwTb, out_newcmem, ncmemb, nullptr, 1024, 4096, 4096, 4096, 1024,
        conv_b, 0, nullptr, nullptr, nullptr);

    // ckb/cvT = bf16(new_cmem @ Wkv)
    mfma_gemm<0, 5><<<dim3(16, 8, 1), blk, 0, stream>>>(
        ncmemb, WkvTb, nullptr, ckb, cvT, 2048, 1024, 1024, 1024, 2048,
        nullptr, 128, nullptr, nullptr, nullptr);

    // fused attention with XCD-chunked swizzle
    attn_fused16<<<dim3(4096), blk, 0, stream>>>(qb, kb, peb, vTb, out_weights, oatb);

    // logits = oat @ Wout + bout (non-temporal output)
    mfma_gemm<0, 6><<<dim3(8, 32, 1), blk, 0, stream>>>(
        oatb, WoutTb, out_logits, nullptr, nullptr, 1024, 1024, 1024, 1024, 1024,
        bout, 0, nullptr, nullptr, nullptr);

    // new_mem = x (non-temporal)
    copy_kernel<<<dim3(4096), blk, 0, stream>>>(out_newmem, x, 1048576);

    // aux loss
    aux_mfma_kernel<<<dim3(4, 128), blk, 0, stream>>>(qb, kb, ckb, vTb, cvT, partials);
    aux_reduce_kernel<<<dim3(1), blk, 0, stream>>>(partials, out_aux);
}

// Round 16
// 594.407 us; speedup vs baseline: 1.2305x; 1.1416x over previous
//
#include <hip/hip_runtime.h>
#include <cstdint>

// HEADS=16, DIM=1024, SEQ=512, MEM=512, CMEM=128, RATIO=4, DIM_H=64, b=8, kv_len=1152

typedef __bf16 bf16;
typedef __bf16 bf16x2 __attribute__((ext_vector_type(2)));
typedef __bf16 bf16x4 __attribute__((ext_vector_type(4)));
typedef __bf16 bf16x8 __attribute__((ext_vector_type(8)));
typedef float  f32x2  __attribute__((ext_vector_type(2)));
typedef float  f32x4  __attribute__((ext_vector_type(4)));

// ---------------------------------------------------------------------------
// MFMA GEMM: C[M,N] = A[M,K] @ B[K,N], tile 128x128, BK=32, 4 waves.
// EPI 8: split-K partial — blockIdx.z selects K-slice of size K; fp32 partial
//        written to C at slice offset z*(1<<20). (ldc==1024 fixed)
// ---------------------------------------------------------------------------
template<int AMODE, int EPI>
__global__ __launch_bounds__(256)
void mfma_gemm(const bf16* __restrict__ A, const bf16* __restrict__ B2,
               float* __restrict__ C, bf16* __restrict__ outB, bf16* __restrict__ vT,
               int N, int K, int lda, int ldbt, int ldc,
               const float* __restrict__ bias, int vrows,
               const bf16* __restrict__ gcmem, const bf16* __restrict__ gmem,
               const bf16* __restrict__ gx)
{
    int row0 = blockIdx.y * 128, col0 = blockIdx.x * 128;
    int tid = threadIdx.x;
    int kofs = (EPI == 8) ? blockIdx.z * K : 0;

    __shared__ bf16 As[128][72];
    __shared__ bf16 Bs[128][72];

    int rn_ = tid >> 2;           // 0..63
    int c8  = (tid & 3) * 8;      // k-chunk (bf16)

    const bf16* aptr[2];
#pragma unroll
    for (int jj = 0; jj < 2; jj++) {
        int gr = row0 + rn_ + 64 * jj;
        if (AMODE == 0) {
            aptr[jj] = A + (long)gr * lda + kofs;
        } else {
            int bb = gr / 1152, rr = gr - bb * 1152;
            aptr[jj] = (rr < 128) ? (gcmem + ((long)bb * 128 + rr) * 1024)
                     : (rr < 640) ? (gmem + ((long)bb * 512 + (rr - 128)) * 1024)
                                  : (gx   + ((long)bb * 512 + (rr - 640)) * 1024);
        }
    }
    const bf16* bptr[2];
#pragma unroll
    for (int jj = 0; jj < 2; jj++) {
        int gc = col0 + rn_ + 64 * jj;
        bptr[jj] = (gc < N) ? (B2 + (long)gc * ldbt + kofs + c8) : nullptr;
    }

    int lane = tid & 63, wid = tid >> 6;
    int wr = wid >> 1, wc = wid & 1;
    int fr = lane & 15, fq = lane >> 4;

    f32x4 acc[4][4];
#pragma unroll
    for (int i = 0; i < 4; i++)
#pragma unroll
        for (int j = 0; j < 4; j++) acc[i][j] = (f32x4){0.f, 0.f, 0.f, 0.f};

    for (int k0 = 0; k0 < K; k0 += 32) {
#pragma unroll
        for (int jj = 0; jj < 2; jj++) {
            bf16x8 v = *(const bf16x8*)(aptr[jj] + k0 + c8);
            *(bf16x8*)&As[rn_ + 64 * jj][c8] = v;
        }
#pragma unroll
        for (int jj = 0; jj < 2; jj++) {
            bf16x8 v = {};
            if (bptr[jj]) v = *(const bf16x8*)(bptr[jj] + k0);
            *(bf16x8*)&Bs[rn_ + 64 * jj][c8] = v;
        }
        __syncthreads();

        bf16x8 af[4], bfv[4];
#pragma unroll
        for (int i = 0; i < 4; i++)
            af[i] = *(const bf16x8*)&As[wr * 64 + i * 16 + fr][fq * 8];
#pragma unroll
        for (int j = 0; j < 4; j++)
            bfv[j] = *(const bf16x8*)&Bs[wc * 64 + j * 16 + fr][fq * 8];
#pragma unroll
        for (int i = 0; i < 4; i++)
#pragma unroll
            for (int j = 0; j < 4; j++)
                acc[i][j] = __builtin_amdgcn_mfma_f32_16x16x32_bf16(af[i], bfv[j], acc[i][j], 0, 0, 0);
        __syncthreads();
    }

#pragma unroll
    for (int i = 0; i < 4; i++) {
#pragma unroll
        for (int j = 0; j < 4; j++) {
#pragma unroll
            for (int g = 0; g < 4; g++) {
                int r = row0 + wr * 64 + i * 16 + fq * 4 + g;
                int c = col0 + wc * 64 + j * 16 + fr;
                float v = acc[i][j][g];
                if (EPI == 0) {
                    if (c < N) {
                        if (bias) v += bias[c];
                        C[(long)r * ldc + c] = v;
                    }
                } else if (EPI == 6) {
                    if (c < N) {
                        if (bias) v += bias[c];
                        __builtin_nontemporal_store(v, &C[(long)r * ldc + c]);
                    }
                } else if (EPI == 8) {
                    C[((long)blockIdx.z << 20) + (long)r * 1024 + c] = v;
                } else if (EPI == 4) {
                    if (c < N) outB[(long)r * ldc + c] = (bf16)v;
                } else { // EPI == 5
                    if (c < 1024) {
                        outB[(long)r * 1024 + c] = (bf16)v;
                    } else {
                        int d = c - 1024; int hh = d >> 6; d &= 63;
                        int bb = r / vrows; int j2 = r - bb * vrows;
                        vT[(((long)(bb * 16 + hh)) * 64 + d) * vrows + j2] = (bf16)v;
                    }
                }
            }
        }
    }
}

// split-K reduce: newcmem = sum of 4 partials + conv_b (fp32) and bf16 copy
__global__ __launch_bounds__(256)
void splitk_reduce(const float* __restrict__ pbuf, const float* __restrict__ bias,
                   float* __restrict__ outF, bf16* __restrict__ outB)
{
    int i = blockIdx.x * 256 + threadIdx.x;      // f32x4 index, 262144 total
    f32x4 s = reinterpret_cast<const f32x4*>(pbuf)[i];
#pragma unroll
    for (int k = 1; k < 4; k++) {
        f32x4 t = reinterpret_cast<const f32x4*>(pbuf + (long)k * 1048576)[i];
        s[0] += t[0]; s[1] += t[1]; s[2] += t[2]; s[3] += t[3];
    }
    int col4 = (i << 2) & 1023;
    f32x4 bv = *(const f32x4*)&bias[col4];
    s[0] += bv[0]; s[1] += bv[1]; s[2] += bv[2]; s[3] += bv[3];
    reinterpret_cast<f32x4*>(outF)[i] = s;
    bf16x4 h = { (bf16)s[0], (bf16)s[1], (bf16)s[2], (bf16)s[3] };
    reinterpret_cast<bf16x4*>(outB)[i] = h;
}

// fp32 [R][C] -> bf16 [C][R]
__global__ __launch_bounds__(256)
void transpose_cast(const float* __restrict__ in, bf16* __restrict__ out, int R, int C)
{
    __shared__ float t[32][33];
    int c0 = blockIdx.x * 32, r0 = blockIdx.y * 32;
    int tx = threadIdx.x & 31, ty = threadIdx.x >> 5;
#pragma unroll
    for (int i = 0; i < 32; i += 8)
        t[ty + i][tx] = in[(long)(r0 + ty + i) * C + c0 + tx];
    __syncthreads();
#pragma unroll
    for (int i = 0; i < 32; i += 8)
        out[(long)(c0 + ty + i) * R + r0 + tx] = (bf16)t[tx][ty + i];
}

// conv_w [o][i][r] -> bf16 [o][r*1024+i], LDS-staged (coalesced global read)
__global__ __launch_bounds__(256)
void convw_cast(const float* __restrict__ cw, bf16* __restrict__ out)
{
    long o = blockIdx.x;
    const float* src = cw + o * 4096;
    bf16* dst = out + o * 4096;
    __shared__ float t[4096];
#pragma unroll
    for (int k = 0; k < 4; k++)
        *(f32x4*)&t[(threadIdx.x + k * 256) * 4] = *(const f32x4*)&src[(threadIdx.x + k * 256) * 4];
    __syncthreads();
#pragma unroll
    for (int k = 0; k < 8; k++) {
        int d2 = 2 * (threadIdx.x + k * 256);
        int pi = ((d2 & 1023) << 2) | (d2 >> 10);
        bf16x2 h = { (bf16)t[pi], (bf16)t[pi + 4] };
        *(bf16x2*)&dst[d2] = h;
    }
}

// merged segmented fp32 -> bf16 cast: pe | x | mem | cmem in one launch
__global__ __launch_bounds__(256)
void cast_f2b_multi(const float* __restrict__ s0, bf16* __restrict__ d0, int n0,
                    const float* __restrict__ s1, bf16* __restrict__ d1, int n1,
                    const float* __restrict__ s2, bf16* __restrict__ d2, int n2,
                    const float* __restrict__ s3, bf16* __restrict__ d3, int n3)
{
    int i = blockIdx.x * 256 + threadIdx.x;
    int stride = gridDim.x * 256;
    int ntot = n0 + n1 + n2 + n3;
    for (; i < ntot; i += stride) {
        const float* src; bf16* dst; int k = i;
        if (k < n0) { src = s0; dst = d0; }
        else if ((k -= n0) < n1) { src = s1; dst = d1; }
        else if ((k -= n1) < n2) { src = s2; dst = d2; }
        else { k -= n2; src = s3; dst = d3; }
        float4 f = reinterpret_cast<const float4*>(src)[k];
        bf16x4 h = { (bf16)f.x, (bf16)f.y, (bf16)f.z, (bf16)f.w };
        reinterpret_cast<bf16x4*>(dst)[k] = h;
    }
}

// ---------------------------------------------------------------------------
// Fused attention (round-10 best): 16 q-rows/block, 4 waves, XCD swizzle,
// S in LDS, vectorized softmax, NT tail weights write.
// ---------------------------------------------------------------------------
#define SSTR 1164

__global__ __launch_bounds__(256)
void attn_fused16(const bf16* __restrict__ qb, const bf16* __restrict__ kb,
                  const bf16* __restrict__ peb, const bf16* __restrict__ vTb,
                  float* __restrict__ weights, bf16* __restrict__ oatb)
{
    int bid = blockIdx.x;
    int w = (bid & 7) * 512 + (bid >> 3);
    int z = w >> 5;
    int b = z >> 4, h = z & 15;
    int r0 = (w & 31) * 16;
    int tid = threadIdx.x;
    int lane = tid & 63, wid = tid >> 6;
    int fr = lane & 15, fq = lane >> 4;

    __shared__ bf16 S[16 * SSTR];

    bf16x8 afr[2];
#pragma unroll
    for (int ks = 0; ks < 2; ks++)
        afr[ks] = *(const bf16x8*)&qb[((long)(b * 512 + r0 + fr)) * 1024 + h * 64 + ks * 32 + fq * 8];

#pragma unroll 3
    for (int ch = 0; ch < 9; ch++) {
        int c0 = ch * 128;
        int jb0 = c0 + 496 - r0 + 32 * wid;

        f32x4 p[3];
#pragma unroll
        for (int ct = 0; ct < 3; ct++) {
            f32x4 a = (f32x4){0.f, 0.f, 0.f, 0.f};
            int j = jb0 + ct * 16 + fr;
            bool ok = (j < 1152);
#pragma unroll
            for (int ks = 0; ks < 2; ks++) {
                bf16x8 bv = {};
                if (ok) bv = *(const bf16x8*)&peb[((long)(h * 1152 + j)) * 64 + ks * 32 + fq * 8];
                a = __builtin_amdgcn_mfma_f32_16x16x32_bf16(afr[ks], bv, a, 0, 0, 0);
            }
            p[ct] = a;
        }

#pragma unroll
        for (int tt = 0; tt < 2; tt++) {
            int cc = 32 * wid + 16 * tt + fr;
            f32x4 a = (f32x4){0.f, 0.f, 0.f, 0.f};
            long krow = (long)(b * 1152 + c0 + cc);
#pragma unroll
            for (int ks = 0; ks < 2; ks++) {
                bf16x8 bv = *(const bf16x8*)&kb[krow * 1024 + h * 64 + ks * 32 + fq * 8];
                a = __builtin_amdgcn_mfma_f32_16x16x32_bf16(afr[ks], bv, a, 0, 0, 0);
            }
#pragma unroll
            for (int g = 0; g < 4; g++) {
                int rr = fq * 4 + g;
                int uu = fr + 15 - rr;
                int src = (uu & 15) | (fq << 4);
                float s0 = __shfl(p[tt][g], src, 64);
                float s1 = __shfl(p[tt + 1][g], src, 64);
                float pv = (uu < 16) ? s0 : s1;
                S[rr * SSTR + c0 + cc] = (bf16)(0.125f * (a[g] + pv));
            }
        }
    }
    __syncthreads();

    for (int rw = 0; rw < 4; rw++) {
        int row = wid * 4 + rw;
        bf16* Srow = &S[row * SSTR];
        bf16x8 v0 = *(const bf16x8*)&Srow[lane * 8];
        bf16x8 v1 = *(const bf16x8*)&Srow[512 + lane * 8];
        bf16x2 v2 = *(const bf16x2*)&Srow[1024 + lane * 2];
        float e[18];
#pragma unroll
        for (int j = 0; j < 8; j++) { e[j] = (float)v0[j]; e[8 + j] = (float)v1[j]; }
        e[16] = (float)v2[0]; e[17] = (float)v2[1];

        float m = e[0];
#pragma unroll
        for (int k = 1; k < 18; k++) m = fmaxf(m, e[k]);
#pragma unroll
        for (int off = 32; off; off >>= 1) m = fmaxf(m, __shfl_xor(m, off, 64));
        float sm = 0.f;
#pragma unroll
        for (int k = 0; k < 18; k++) { e[k] = __expf(e[k] - m); sm += e[k]; }
#pragma unroll
        for (int off = 32; off; off >>= 1) sm += __shfl_xor(sm, off, 64);
        float inv = 1.f / sm;

        bf16x8 w0, w1; bf16x2 w2;
#pragma unroll
        for (int j = 0; j < 8; j++) { w0[j] = (bf16)(e[j] * inv); w1[j] = (bf16)(e[8 + j] * inv); }
        w2[0] = (bf16)(e[16] * inv); w2[1] = (bf16)(e[17] * inv);
        *(bf16x8*)&Srow[lane * 8] = w0;
        *(bf16x8*)&Srow[512 + lane * 8] = w1;
        *(bf16x2*)&Srow[1024 + lane * 2] = w2;
    }
    __syncthreads();

    f32x4 oacc = (f32x4){0.f, 0.f, 0.f, 0.f};
    int dt = wid;
    for (int ch = 0; ch < 9; ch++) {
        int c0 = ch * 128;
#pragma unroll
        for (int ks = 0; ks < 4; ks++) {
            bf16x8 pa = *(const bf16x8*)&S[fr * SSTR + c0 + ks * 32 + fq * 8];
            bf16x8 vb = *(const bf16x8*)&vTb[((long)z * 64 + dt * 16 + fr) * 1152 + c0 + ks * 32 + fq * 8];
            oacc = __builtin_amdgcn_mfma_f32_16x16x32_bf16(pa, vb, oacc, 0, 0, 0);
        }
    }
#pragma unroll
    for (int g = 0; g < 4; g++)
        oatb[((long)(b * 512 + r0 + fq * 4 + g)) * 1024 + h * 64 + dt * 16 + fr] = (bf16)oacc[g];

    for (int rw = 0; rw < 4; rw++) {
        int row = wid * 4 + rw;
        const bf16* Srow = &S[row * SSTR];
        long wbase = ((long)z * 512 + r0 + row) * 1152;
        bf16x8 v0 = *(const bf16x8*)&Srow[lane * 8];
        bf16x8 v1 = *(const bf16x8*)&Srow[512 + lane * 8];
        bf16x2 v2 = *(const bf16x2*)&Srow[1024 + lane * 2];
        f32x4 a0 = { (float)v0[0], (float)v0[1], (float)v0[2], (float)v0[3] };
        f32x4 a1 = { (float)v0[4], (float)v0[5], (float)v0[6], (float)v0[7] };
        f32x4 b0 = { (float)v1[0], (float)v1[1], (float)v1[2], (float)v1[3] };
        f32x4 b1 = { (float)v1[4], (float)v1[5], (float)v1[6], (float)v1[7] };
        f32x2 c0 = { (float)v2[0], (float)v2[1] };
        __builtin_nontemporal_store(a0, (f32x4*)&weights[wbase + lane * 8]);
        __builtin_nontemporal_store(a1, (f32x4*)&weights[wbase + lane * 8 + 4]);
        __builtin_nontemporal_store(b0, (f32x4*)&weights[wbase + 512 + lane * 8]);
        __builtin_nontemporal_store(b1, (f32x4*)&weights[wbase + 512 + lane * 8 + 4]);
        __builtin_nontemporal_store(c0, (f32x2*)&weights[wbase + 1024 + lane * 2]);
    }
}

// ---------------------------------------------------------------------------
// Fused MFMA aux loss (round-10 version, verified)
// ---------------------------------------------------------------------------
__global__ __launch_bounds__(256)
void aux_mfma_kernel(const bf16* __restrict__ qb, const bf16* __restrict__ kb,
                     const bf16* __restrict__ ckb,
                     const bf16* __restrict__ vTb, const bf16* __restrict__ cvT,
                     float* __restrict__ partials)
{
    int z = blockIdx.y;
    int b = z >> 4, h = z & 15;
    int r0 = blockIdx.x * 128;
    int tid = threadIdx.x;
    int lane = tid & 63, wid = tid >> 6;
    int fr = lane & 15, fq = lane >> 4;

    __shared__ bf16 qs[128][72];
    __shared__ bf16 upool[128 * 136];
    __shared__ bf16 vt[64][136];
    __shared__ float wred[4];

#pragma unroll
    for (int t = 0; t < 4; t++) {
        int e = tid + 256 * t; int rr = e >> 3, c8 = (e & 7) * 8;
        *(bf16x8*)&qs[rr][c8] = *(const bf16x8*)&qb[((long)(b * 512 + r0 + rr)) * 1024 + h * 64 + c8];
    }

    float o1[2][4][4];
    f32x4 oaccv[2][4];
    float mrow[2][4], lrow[2][4];
    f32x4 sacc[2][8];
    float local = 0.f;

    for (int pass = 0; pass < 2; pass++) {
#pragma unroll
        for (int i = 0; i < 2; i++)
#pragma unroll
            for (int g = 0; g < 4; g++) { mrow[i][g] = -3.4e38f; lrow[i][g] = 0.f; }
#pragma unroll
        for (int i = 0; i < 2; i++)
#pragma unroll
            for (int jd = 0; jd < 4; jd++) oaccv[i][jd] = (f32x4){0.f, 0.f, 0.f, 0.f};

        int nchunk = pass ? 1 : 4;
        for (int jt = 0; jt < nchunk; jt++) {
            __syncthreads();
            if (pass == 0) {
                long base = (long)(b * 1152 + 128 + jt * 128);
#pragma unroll
                for (int t = 0; t < 4; t++) {
                    int e = tid + 256 * t; int j = e >> 3, c8 = (e & 7) * 8;
                    *(bf16x8*)&upool[j * 72 + c8] = *(const bf16x8*)&kb[(base + j) * 1024 + h * 64 + c8];
                }
#pragma unroll
                for (int t = 0; t < 4; t++) {
                    int e = tid + 256 * t; int d = e >> 4, j8 = (e & 15) * 8;
                    *(bf16x8*)&vt[d][j8] =
                        *(const bf16x8*)&vTb[((long)z * 64 + d) * 1152 + 128 + jt * 128 + j8];
                }
            } else {
#pragma unroll
                for (int t = 0; t < 4; t++) {
                    int e = tid + 256 * t; int j = e >> 3, c8 = (e & 7) * 8;
                    *(bf16x8*)&upool[j * 72 + c8] = *(const bf16x8*)&ckb[((long)(b * 128 + j)) * 1024 + h * 64 + c8];
                }
#pragma unroll
                for (int t = 0; t < 4; t++) {
                    int e = tid + 256 * t; int d = e >> 4, j8 = (e & 15) * 8;
                    *(bf16x8*)&vt[d][j8] = *(const bf16x8*)&cvT[((long)z * 64 + d) * 128 + j8];
                }
            }
            __syncthreads();

#pragma unroll
            for (int i = 0; i < 2; i++)
#pragma unroll
                for (int j = 0; j < 8; j++) sacc[i][j] = (f32x4){0.f, 0.f, 0.f, 0.f};
#pragma unroll
            for (int s = 0; s < 2; s++) {
                bf16x8 af[2], bfv[8];
#pragma unroll
                for (int i = 0; i < 2; i++)
                    af[i] = *(const bf16x8*)&qs[wid * 32 + i * 16 + fr][s * 32 + fq * 8];
#pragma unroll
                for (int j = 0; j < 8; j++)
                    bfv[j] = *(const bf16x8*)&upool[(j * 16 + fr) * 72 + s * 32 + fq * 8];
#pragma unroll
                for (int i = 0; i < 2; i++)
#pragma unroll
                    for (int j = 0; j < 8; j++)
                        sacc[i][j] = __builtin_amdgcn_mfma_f32_16x16x32_bf16(af[i], bfv[j], sacc[i][j], 0, 0, 0);
            }
            __syncthreads();

#pragma unroll
            for (int i = 0; i < 2; i++) {
#pragma unroll
                for (int g = 0; g < 4; g++) {
                    float mx = -3.4e38f;
#pragma unroll
                    for (int j = 0; j < 8; j++) mx = fmaxf(mx, sacc[i][j][g]);
                    mx *= 0.125f;
#pragma unroll
                    for (int msk = 1; msk <= 8; msk <<= 1) mx = fmaxf(mx, __shfl_xor(mx, msk, 64));
                    float mnew = fmaxf(mrow[i][g], mx);
                    float alpha = __expf(mrow[i][g] - mnew);
                    mrow[i][g] = mnew;
                    float sum = 0.f;
                    int prow = (wid * 32 + i * 16 + fq * 4 + g) * 136;
#pragma unroll
                    for (int j = 0; j < 8; j++) {
                        float p = __expf(sacc[i][j][g] * 0.125f - mnew);
                        sum += p;
                        upool[prow + j * 16 + fr] = (bf16)p;
                    }
#pragma unroll
                    for (int msk = 1; msk <= 8; msk <<= 1) sum += __shfl_xor(sum, msk, 16);
                    lrow[i][g] = lrow[i][g] * alpha + sum;
#pragma unroll
                    for (int jd = 0; jd < 4; jd++) oaccv[i][jd][g] *= alpha;
                }
            }
            __syncthreads();

#pragma unroll
            for (int s2 = 0; s2 < 4; s2++) {
                bf16x8 pa[2], vb[4];
#pragma unroll
                for (int i = 0; i < 2; i++)
                    pa[i] = *(const bf16x8*)&upool[(wid * 32 + i * 16 + fr) * 136 + s2 * 32 + fq * 8];
#pragma unroll
                for (int jd = 0; jd < 4; jd++)
                    vb[jd] = *(const bf16x8*)&vt[jd * 16 + fr][s2 * 32 + fq * 8];
#pragma unroll
                for (int i = 0; i < 2; i++)
#pragma unroll
                    for (int jd = 0; jd < 4; jd++)
                        oaccv[i][jd] = __builtin_amdgcn_mfma_f32_16x16x32_bf16(pa[i], vb[jd], oaccv[i][jd], 0, 0, 0);
            }
        }

        if (pass == 0) {
#pragma unroll
            for (int i = 0; i < 2; i++)
#pragma unroll
                for (int jd = 0; jd < 4; jd++)
#pragma unroll
                    for (int g = 0; g < 4; g++)
                        o1[i][jd][g] = oaccv[i][jd][g] / lrow[i][g];
        } else {
#pragma unroll
            for (int i = 0; i < 2; i++)
#pragma unroll
                for (int jd = 0; jd < 4; jd++)
#pragma unroll
                    for (int g = 0; g < 4; g++) {
                        float dd = o1[i][jd][g] - oaccv[i][jd][g] / lrow[i][g];
                        local += dd * dd;
                    }
        }
    }

#pragma unroll
    for (int off = 32; off; off >>= 1) local += __shfl_xor(local, off, 64);
    if (lane == 0) wred[wid] = local;
    __syncthreads();
    if (tid == 0)
        partials[(long)blockIdx.y * 4 + blockIdx.x] = wred[0] + wred[1] + wred[2] + wred[3];
}

__global__ __launch_bounds__(256)
void aux_reduce_kernel(const float* __restrict__ partials, float* __restrict__ out)
{
    int tid = threadIdx.x;
    __shared__ float wred[4];
    float s = 0.f;
    for (int i = tid; i < 512; i += 256) s += partials[i];
#pragma unroll
    for (int off = 32; off; off >>= 1) s += __shfl_xor(s, off, 64);
    if ((tid & 63) == 0) wred[tid >> 6] = s;
    __syncthreads();
    if (tid == 0) out[0] = (wred[0] + wred[1] + wred[2] + wred[3]) * (1.0f / 4194304.0f);
}

__global__ __launch_bounds__(256)
void copy_kernel(float* __restrict__ dst, const float* __restrict__ src, int n4)
{
    int i = blockIdx.x * 256 + threadIdx.x;
    int stride = gridDim.x * 256;
    for (; i < n4; i += stride) {
        f32x4 v = reinterpret_cast<const f32x4*>(src)[i];
        __builtin_nontemporal_store(v, &reinterpret_cast<f32x4*>(dst)[i]);
    }
}

extern "C" void kernel_launch(void* const* d_in, const int* in_sizes, int n_in,
                              void* d_out, int out_size, void* d_ws, size_t ws_size,
                              hipStream_t stream)
{
    const float* x      = (const float*)d_in[0];
    const float* mem    = (const float*)d_in[1];
    const float* cmem   = (const float*)d_in[2];
    const float* pe     = (const float*)d_in[3];
    const float* Wq     = (const float*)d_in[4];
    const float* Wkv    = (const float*)d_in[5];
    const float* Wout   = (const float*)d_in[6];
    const float* bout   = (const float*)d_in[7];
    const float* conv_w = (const float*)d_in[8];
    const float* conv_b = (const float*)d_in[9];

    float* out_logits  = (float*)d_out;                 // 8*512*1024
    float* out_newmem  = out_logits + 4194304;          // 8*512*1024
    float* out_newcmem = out_newmem + 4194304;          // 8*128*1024
    float* out_aux     = out_newcmem + 1048576;         // 1
    float* out_weights = out_aux + 1;                   // 8*16*512*1152

    float* ws       = (float*)d_ws;
    float* partials = ws;                    // 4096 f
    float* pbuf     = partials + 4096;       // 4 * 1,048,576 f (split-K partials)
    bf16* bws     = (bf16*)(pbuf + 4194304);
    bf16* WqTb    = bws;                     // 1,048,576
    bf16* WkvTb   = WqTb + 1048576;          // 2,097,152
    bf16* WoutTb  = WkvTb + 2097152;         // 1,048,576
    bf16* convwTb = WoutTb + 1048576;        // 4,194,304
    bf16* vTb     = convwTb + 4194304;       // 9,437,184
    bf16* cvT     = vTb + 9437184;           // 1,048,576
    bf16* qb      = cvT + 1048576;           // 4,194,304
    bf16* kb      = qb + 4194304;            // 9,437,184
    bf16* ckb     = kb + 9437184;            // 1,048,576
    bf16* peb     = ckb + 1048576;           // 1,179,648
    bf16* xb      = peb + 1179648;           // 4,194,304
    bf16* memb    = xb + 4194304;            // 4,194,304
    bf16* cmemb   = memb + 4194304;          // 1,048,576
    bf16* ncmemb  = cmemb + 1048576;         // 1,048,576
    bf16* oatb    = ncmemb + 1048576;        // 4,194,304

    dim3 blk(256);

    transpose_cast<<<dim3(32, 32), blk, 0, stream>>>(Wq, WqTb, 1024, 1024);
    transpose_cast<<<dim3(64, 32), blk, 0, stream>>>(Wkv, WkvTb, 1024, 2048);
    transpose_cast<<<dim3(32, 32), blk, 0, stream>>>(Wout, WoutTb, 1024, 1024);
    convw_cast<<<dim3(1024), blk, 0, stream>>>(conv_w, convwTb);
    // merged input casts: pe | x | mem | cmem
    cast_f2b_multi<<<dim3(2048), blk, 0, stream>>>(
        pe, peb, 294912, x, xb, 1048576, mem, memb, 1048576, cmem, cmemb, 262144);

    // qb = bf16(x @ Wq)
    mfma_gemm<0, 4><<<dim3(8, 32, 1), blk, 0, stream>>>(
        xb, WqTb, nullptr, qb, nullptr, 1024, 1024, 1024, 1024, 1024,
        nullptr, 0, nullptr, nullptr, nullptr);

    // kb/vTb = bf16(concat(cmem,mem,x) @ Wkv)
    mfma_gemm<1, 5><<<dim3(16, 72, 1), blk, 0, stream>>>(
        nullptr, WkvTb, nullptr, kb, vTb, 2048, 1024, 1024, 1024, 2048,
        nullptr, 1152, cmemb, memb, xb);

    // conv-compress GEMM, split-K: 4 slices of K=1024 -> fp32 partials
    mfma_gemm<0, 8><<<dim3(8, 8, 4), blk, 0, stream>>>(
        memb, convwTb, pbuf, nullptr, nullptr, 1024, 1024, 4096, 4096, 1024,
        nullptr, 0, nullptr, nullptr, nullptr);
    // reduce partials + bias -> new_cmem (fp32) + ncmemb (bf16)
    splitk_reduce<<<dim3(1024), blk, 0, stream>>>(pbuf, conv_b, out_newcmem, ncmemb);

    // ckb/cvT = bf16(new_cmem @ Wkv)
    mfma_gemm<0, 5><<<dim3(16, 8, 1), blk, 0, stream>>>(
        ncmemb, WkvTb, nullptr, ckb, cvT, 2048, 1024, 1024, 1024, 2048,
        nullptr, 128, nullptr, nullptr, nullptr);

    // fused attention with XCD-chunked swizzle
    attn_fused16<<<dim3(4096), blk, 0, stream>>>(qb, kb, peb, vTb, out_weights, oatb);

    // logits = oat @ Wout + bout (non-temporal output)
    mfma_gemm<0, 6><<<dim3(8, 32, 1), blk, 0, stream>>>(
        oatb, WoutTb, out_logits, nullptr, nullptr, 1024, 1024, 1024, 1024, 1024,
        bout, 0, nullptr, nullptr, nullptr);

    // new_mem = x (non-temporal)
    copy_kernel<<<dim3(4096), blk, 0, stream>>>(out_newmem, x, 1048576);

    // aux loss
    aux_mfma_kernel<<<dim3(4, 128), blk, 0, stream>>>(qb, kb, ckb, vTb, cvT, partials);
    aux_reduce_kernel<<<dim3(1), blk, 0, stream>>>(partials, out_aux);
}

// Round 17
// 533.846 us; speedup vs baseline: 1.3701x; 1.1134x over previous
//
#include <hip/hip_runtime.h>
#include <cstdint>

// HEADS=16, DIM=1024, SEQ=512, MEM=512, CMEM=128, RATIO=4, DIM_H=64, b=8, kv_len=1152

typedef __bf16 bf16;
typedef __bf16 bf16x2 __attribute__((ext_vector_type(2)));
typedef __bf16 bf16x4 __attribute__((ext_vector_type(4)));
typedef __bf16 bf16x8 __attribute__((ext_vector_type(8)));
typedef float  f32x2  __attribute__((ext_vector_type(2)));
typedef float  f32x4  __attribute__((ext_vector_type(4)));

#define GLOAD_LDS16(g, l) \
    __builtin_amdgcn_global_load_lds((const __attribute__((address_space(1))) void*)(g), \
                                     (__attribute__((address_space(3))) void*)(l), 16, 0, 0)

// ---------------------------------------------------------------------------
// MFMA GEMM: C[M,N] = A[M,K] @ B[K,N], tile 128x128, BK=32, 4 waves.
// Staging via global_load_lds (width 16) into linear LDS with XOR-swizzled
// source: chunk c16 of row r stored at c16 ^ ((r>>1)&3). Fragment reads apply
// the same XOR -> 2-way bank aliasing (free).
// EPI 8: split-K partial (blockIdx.z selects K-slice; partial at z<<20).
// NOTE: all N are multiples of 128 in this problem (no bounds checks).
// ---------------------------------------------------------------------------
template<int AMODE, int EPI>
__global__ __launch_bounds__(256)
void mfma_gemm(const bf16* __restrict__ A, const bf16* __restrict__ B2,
               float* __restrict__ C, bf16* __restrict__ outB, bf16* __restrict__ vT,
               int N, int K, int lda, int ldbt, int ldc,
               const float* __restrict__ bias, int vrows,
               const bf16* __restrict__ gcmem, const bf16* __restrict__ gmem,
               const bf16* __restrict__ gx)
{
    int row0 = blockIdx.y * 128, col0 = blockIdx.x * 128;
    int tid = threadIdx.x;
    int kofs = (EPI == 8) ? blockIdx.z * K : 0;

    __shared__ bf16 As[128 * 32];
    __shared__ bf16 Bs[128 * 32];

    int lane = tid & 63, wid = tid >> 6;
    int wr = wid >> 1, wc = wid & 1;
    int fr = lane & 15, fq = lane >> 4;

    // staging source addresses (per lane): inst t covers rows [wid*32+t*16, +16)
    int srow = lane >> 2;                       // 0..15 within inst
    int sc16 = (lane & 3) ^ ((lane >> 3) & 3);  // swizzled source 16B chunk
    const bf16* aq[2];
    const bf16* bq[2];
    bf16* as_dst[2];
    bf16* bs_dst[2];
#pragma unroll
    for (int t = 0; t < 2; t++) {
        int gr = row0 + wid * 32 + t * 16 + srow;
        const bf16* ap;
        if (AMODE == 0) {
            ap = A + (long)gr * lda + kofs;
        } else {
            int bb = gr / 1152, rr = gr - bb * 1152;
            ap = (rr < 128) ? (gcmem + ((long)bb * 128 + rr) * 1024)
               : (rr < 640) ? (gmem + ((long)bb * 512 + (rr - 128)) * 1024)
                            : (gx   + ((long)bb * 512 + (rr - 640)) * 1024);
        }
        aq[t] = ap + sc16 * 8;
        int gc = col0 + wid * 32 + t * 16 + srow;
        bq[t] = B2 + (long)gc * ldbt + kofs + sc16 * 8;
        as_dst[t] = &As[(wid * 32 + t * 16) * 32];
        bs_dst[t] = &Bs[(wid * 32 + t * 16) * 32];
    }

    int sfq = (fq ^ ((fr >> 1) & 3)) * 8;   // swizzled fragment chunk offset

    f32x4 acc[4][4];
#pragma unroll
    for (int i = 0; i < 4; i++)
#pragma unroll
        for (int j = 0; j < 4; j++) acc[i][j] = (f32x4){0.f, 0.f, 0.f, 0.f};

    for (int k0 = 0; k0 < K; k0 += 32) {
#pragma unroll
        for (int t = 0; t < 2; t++) {
            GLOAD_LDS16(aq[t] + k0, as_dst[t]);
            GLOAD_LDS16(bq[t] + k0, bs_dst[t]);
        }
        __syncthreads();

        bf16x8 af[4], bfv[4];
#pragma unroll
        for (int i = 0; i < 4; i++)
            af[i] = *(const bf16x8*)&As[(wr * 64 + i * 16 + fr) * 32 + sfq];
#pragma unroll
        for (int j = 0; j < 4; j++)
            bfv[j] = *(const bf16x8*)&Bs[(wc * 64 + j * 16 + fr) * 32 + sfq];
#pragma unroll
        for (int i = 0; i < 4; i++)
#pragma unroll
            for (int j = 0; j < 4; j++)
                acc[i][j] = __builtin_amdgcn_mfma_f32_16x16x32_bf16(af[i], bfv[j], acc[i][j], 0, 0, 0);
        __syncthreads();
    }

#pragma unroll
    for (int i = 0; i < 4; i++) {
#pragma unroll
        for (int j = 0; j < 4; j++) {
#pragma unroll
            for (int g = 0; g < 4; g++) {
                int r = row0 + wr * 64 + i * 16 + fq * 4 + g;
                int c = col0 + wc * 64 + j * 16 + fr;
                float v = acc[i][j][g];
                if (EPI == 0) {
                    if (bias) v += bias[c];
                    C[(long)r * ldc + c] = v;
                } else if (EPI == 6) {
                    if (bias) v += bias[c];
                    __builtin_nontemporal_store(v, &C[(long)r * ldc + c]);
                } else if (EPI == 8) {
                    C[((long)blockIdx.z << 20) + (long)r * 1024 + c] = v;
                } else if (EPI == 4) {
                    outB[(long)r * ldc + c] = (bf16)v;
                } else { // EPI == 5
                    if (c < 1024) {
                        outB[(long)r * 1024 + c] = (bf16)v;
                    } else {
                        int d = c - 1024; int hh = d >> 6; d &= 63;
                        int bb = r / vrows; int j2 = r - bb * vrows;
                        vT[(((long)(bb * 16 + hh)) * 64 + d) * vrows + j2] = (bf16)v;
                    }
                }
            }
        }
    }
}

// split-K reduce: newcmem = sum of 4 partials + conv_b (fp32) and bf16 copy
__global__ __launch_bounds__(256)
void splitk_reduce(const float* __restrict__ pbuf, const float* __restrict__ bias,
                   float* __restrict__ outF, bf16* __restrict__ outB)
{
    int i = blockIdx.x * 256 + threadIdx.x;      // f32x4 index, 262144 total
    f32x4 s = reinterpret_cast<const f32x4*>(pbuf)[i];
#pragma unroll
    for (int k = 1; k < 4; k++) {
        f32x4 t = reinterpret_cast<const f32x4*>(pbuf + (long)k * 1048576)[i];
        s[0] += t[0]; s[1] += t[1]; s[2] += t[2]; s[3] += t[3];
    }
    int col4 = (i << 2) & 1023;
    f32x4 bv = *(const f32x4*)&bias[col4];
    s[0] += bv[0]; s[1] += bv[1]; s[2] += bv[2]; s[3] += bv[3];
    reinterpret_cast<f32x4*>(outF)[i] = s;
    bf16x4 h = { (bf16)s[0], (bf16)s[1], (bf16)s[2], (bf16)s[3] };
    reinterpret_cast<bf16x4*>(outB)[i] = h;
}

// fp32 [R][C] -> bf16 [C][R]
__global__ __launch_bounds__(256)
void transpose_cast(const float* __restrict__ in, bf16* __restrict__ out, int R, int C)
{
    __shared__ float t[32][33];
    int c0 = blockIdx.x * 32, r0 = blockIdx.y * 32;
    int tx = threadIdx.x & 31, ty = threadIdx.x >> 5;
#pragma unroll
    for (int i = 0; i < 32; i += 8)
        t[ty + i][tx] = in[(long)(r0 + ty + i) * C + c0 + tx];
    __syncthreads();
#pragma unroll
    for (int i = 0; i < 32; i += 8)
        out[(long)(c0 + ty + i) * R + r0 + tx] = (bf16)t[tx][ty + i];
}

// conv_w [o][i][r] -> bf16 [o][r*1024+i], LDS-staged (coalesced global read)
__global__ __launch_bounds__(256)
void convw_cast(const float* __restrict__ cw, bf16* __restrict__ out)
{
    long o = blockIdx.x;
    const float* src = cw + o * 4096;
    bf16* dst = out + o * 4096;
    __shared__ float t[4096];
#pragma unroll
    for (int k = 0; k < 4; k++)
        *(f32x4*)&t[(threadIdx.x + k * 256) * 4] = *(const f32x4*)&src[(threadIdx.x + k * 256) * 4];
    __syncthreads();
#pragma unroll
    for (int k = 0; k < 8; k++) {
        int d2 = 2 * (threadIdx.x + k * 256);
        int pi = ((d2 & 1023) << 2) | (d2 >> 10);
        bf16x2 h = { (bf16)t[pi], (bf16)t[pi + 4] };
        *(bf16x2*)&dst[d2] = h;
    }
}

// merged segmented fp32 -> bf16 cast: pe | x(+fp32 NT mirror to new_mem) | mem | cmem
__global__ __launch_bounds__(256)
void cast_f2b_multi(const float* __restrict__ s0, bf16* __restrict__ d0, int n0,
                    const float* __restrict__ s1, bf16* __restrict__ d1, int n1,
                    const float* __restrict__ s2, bf16* __restrict__ d2, int n2,
                    const float* __restrict__ s3, bf16* __restrict__ d3, int n3,
                    float* __restrict__ xmirror)
{
    int i = blockIdx.x * 256 + threadIdx.x;
    int stride = gridDim.x * 256;
    int ntot = n0 + n1 + n2 + n3;
    for (; i < ntot; i += stride) {
        const float* src; bf16* dst; int k = i; int seg;
        if (k < n0) { src = s0; dst = d0; seg = 0; }
        else if ((k -= n0) < n1) { src = s1; dst = d1; seg = 1; }
        else if ((k -= n1) < n2) { src = s2; dst = d2; seg = 2; }
        else { k -= n2; src = s3; dst = d3; seg = 3; }
        f32x4 f = reinterpret_cast<const f32x4*>(src)[k];
        bf16x4 h = { (bf16)f[0], (bf16)f[1], (bf16)f[2], (bf16)f[3] };
        reinterpret_cast<bf16x4*>(dst)[k] = h;
        if (seg == 1)
            __builtin_nontemporal_store(f, &reinterpret_cast<f32x4*>(xmirror)[k]);
    }
}

// ---------------------------------------------------------------------------
// Fused attention (round-10 best): 16 q-rows/block, 4 waves, XCD swizzle,
// S in LDS, vectorized softmax, NT tail weights write.
// ---------------------------------------------------------------------------
#define SSTR 1164

__global__ __launch_bounds__(256)
void attn_fused16(const bf16* __restrict__ qb, const bf16* __restrict__ kb,
                  const bf16* __restrict__ peb, const bf16* __restrict__ vTb,
                  float* __restrict__ weights, bf16* __restrict__ oatb)
{
    int bid = blockIdx.x;
    int w = (bid & 7) * 512 + (bid >> 3);
    int z = w >> 5;
    int b = z >> 4, h = z & 15;
    int r0 = (w & 31) * 16;
    int tid = threadIdx.x;
    int lane = tid & 63, wid = tid >> 6;
    int fr = lane & 15, fq = lane >> 4;

    __shared__ bf16 S[16 * SSTR];

    bf16x8 afr[2];
#pragma unroll
    for (int ks = 0; ks < 2; ks++)
        afr[ks] = *(const bf16x8*)&qb[((long)(b * 512 + r0 + fr)) * 1024 + h * 64 + ks * 32 + fq * 8];

#pragma unroll 3
    for (int ch = 0; ch < 9; ch++) {
        int c0 = ch * 128;
        int jb0 = c0 + 496 - r0 + 32 * wid;

        f32x4 p[3];
#pragma unroll
        for (int ct = 0; ct < 3; ct++) {
            f32x4 a = (f32x4){0.f, 0.f, 0.f, 0.f};
            int j = jb0 + ct * 16 + fr;
            bool ok = (j < 1152);
#pragma unroll
            for (int ks = 0; ks < 2; ks++) {
                bf16x8 bv = {};
                if (ok) bv = *(const bf16x8*)&peb[((long)(h * 1152 + j)) * 64 + ks * 32 + fq * 8];
                a = __builtin_amdgcn_mfma_f32_16x16x32_bf16(afr[ks], bv, a, 0, 0, 0);
            }
            p[ct] = a;
        }

#pragma unroll
        for (int tt = 0; tt < 2; tt++) {
            int cc = 32 * wid + 16 * tt + fr;
            f32x4 a = (f32x4){0.f, 0.f, 0.f, 0.f};
            long krow = (long)(b * 1152 + c0 + cc);
#pragma unroll
            for (int ks = 0; ks < 2; ks++) {
                bf16x8 bv = *(const bf16x8*)&kb[krow * 1024 + h * 64 + ks * 32 + fq * 8];
                a = __builtin_amdgcn_mfma_f32_16x16x32_bf16(afr[ks], bv, a, 0, 0, 0);
            }
#pragma unroll
            for (int g = 0; g < 4; g++) {
                int rr = fq * 4 + g;
                int uu = fr + 15 - rr;
                int src = (uu & 15) | (fq << 4);
                float s0 = __shfl(p[tt][g], src, 64);
                float s1 = __shfl(p[tt + 1][g], src, 64);
                float pv = (uu < 16) ? s0 : s1;
                S[rr * SSTR + c0 + cc] = (bf16)(0.125f * (a[g] + pv));
            }
        }
    }
    __syncthreads();

    for (int rw = 0; rw < 4; rw++) {
        int row = wid * 4 + rw;
        bf16* Srow = &S[row * SSTR];
        bf16x8 v0 = *(const bf16x8*)&Srow[lane * 8];
        bf16x8 v1 = *(const bf16x8*)&Srow[512 + lane * 8];
        bf16x2 v2 = *(const bf16x2*)&Srow[1024 + lane * 2];
        float e[18];
#pragma unroll
        for (int j = 0; j < 8; j++) { e[j] = (float)v0[j]; e[8 + j] = (float)v1[j]; }
        e[16] = (float)v2[0]; e[17] = (float)v2[1];

        float m = e[0];
#pragma unroll
        for (int k = 1; k < 18; k++) m = fmaxf(m, e[k]);
#pragma unroll
        for (int off = 32; off; off >>= 1) m = fmaxf(m, __shfl_xor(m, off, 64));
        float sm = 0.f;
#pragma unroll
        for (int k = 0; k < 18; k++) { e[k] = __expf(e[k] - m); sm += e[k]; }
#pragma unroll
        for (int off = 32; off; off >>= 1) sm += __shfl_xor(sm, off, 64);
        float inv = 1.f / sm;

        bf16x8 w0, w1; bf16x2 w2;
#pragma unroll
        for (int j = 0; j < 8; j++) { w0[j] = (bf16)(e[j] * inv); w1[j] = (bf16)(e[8 + j] * inv); }
        w2[0] = (bf16)(e[16] * inv); w2[1] = (bf16)(e[17] * inv);
        *(bf16x8*)&Srow[lane * 8] = w0;
        *(bf16x8*)&Srow[512 + lane * 8] = w1;
        *(bf16x2*)&Srow[1024 + lane * 2] = w2;
    }
    __syncthreads();

    f32x4 oacc = (f32x4){0.f, 0.f, 0.f, 0.f};
    int dt = wid;
    for (int ch = 0; ch < 9; ch++) {
        int c0 = ch * 128;
#pragma unroll
        for (int ks = 0; ks < 4; ks++) {
            bf16x8 pa = *(const bf16x8*)&S[fr * SSTR + c0 + ks * 32 + fq * 8];
            bf16x8 vb = *(const bf16x8*)&vTb[((long)z * 64 + dt * 16 + fr) * 1152 + c0 + ks * 32 + fq * 8];
            oacc = __builtin_amdgcn_mfma_f32_16x16x32_bf16(pa, vb, oacc, 0, 0, 0);
        }
    }
#pragma unroll
    for (int g = 0; g < 4; g++)
        oatb[((long)(b * 512 + r0 + fq * 4 + g)) * 1024 + h * 64 + dt * 16 + fr] = (bf16)oacc[g];

    for (int rw = 0; rw < 4; rw++) {
        int row = wid * 4 + rw;
        const bf16* Srow = &S[row * SSTR];
        long wbase = ((long)z * 512 + r0 + row) * 1152;
        bf16x8 v0 = *(const bf16x8*)&Srow[lane * 8];
        bf16x8 v1 = *(const bf16x8*)&Srow[512 + lane * 8];
        bf16x2 v2 = *(const bf16x2*)&Srow[1024 + lane * 2];
        f32x4 a0 = { (float)v0[0], (float)v0[1], (float)v0[2], (float)v0[3] };
        f32x4 a1 = { (float)v0[4], (float)v0[5], (float)v0[6], (float)v0[7] };
        f32x4 b0 = { (float)v1[0], (float)v1[1], (float)v1[2], (float)v1[3] };
        f32x4 b1 = { (float)v1[4], (float)v1[5], (float)v1[6], (float)v1[7] };
        f32x2 c0 = { (float)v2[0], (float)v2[1] };
        __builtin_nontemporal_store(a0, (f32x4*)&weights[wbase + lane * 8]);
        __builtin_nontemporal_store(a1, (f32x4*)&weights[wbase + lane * 8 + 4]);
        __builtin_nontemporal_store(b0, (f32x4*)&weights[wbase + 512 + lane * 8]);
        __builtin_nontemporal_store(b1, (f32x4*)&weights[wbase + 512 + lane * 8 + 4]);
        __builtin_nontemporal_store(c0, (f32x2*)&weights[wbase + 1024 + lane * 2]);
    }
}

// ---------------------------------------------------------------------------
// Fused MFMA aux loss (round-10 version, verified)
// ---------------------------------------------------------------------------
__global__ __launch_bounds__(256)
void aux_mfma_kernel(const bf16* __restrict__ qb, const bf16* __restrict__ kb,
                     const bf16* __restrict__ ckb,
                     const bf16* __restrict__ vTb, const bf16* __restrict__ cvT,
                     float* __restrict__ partials)
{
    int z = blockIdx.y;
    int b = z >> 4, h = z & 15;
    int r0 = blockIdx.x * 128;
    int tid = threadIdx.x;
    int lane = tid & 63, wid = tid >> 6;
    int fr = lane & 15, fq = lane >> 4;

    __shared__ bf16 qs[128][72];
    __shared__ bf16 upool[128 * 136];
    __shared__ bf16 vt[64][136];
    __shared__ float wred[4];

#pragma unroll
    for (int t = 0; t < 4; t++) {
        int e = tid + 256 * t; int rr = e >> 3, c8 = (e & 7) * 8;
        *(bf16x8*)&qs[rr][c8] = *(const bf16x8*)&qb[((long)(b * 512 + r0 + rr)) * 1024 + h * 64 + c8];
    }

    float o1[2][4][4];
    f32x4 oaccv[2][4];
    float mrow[2][4], lrow[2][4];
    f32x4 sacc[2][8];
    float local = 0.f;

    for (int pass = 0; pass < 2; pass++) {
#pragma unroll
        for (int i = 0; i < 2; i++)
#pragma unroll
            for (int g = 0; g < 4; g++) { mrow[i][g] = -3.4e38f; lrow[i][g] = 0.f; }
#pragma unroll
        for (int i = 0; i < 2; i++)
#pragma unroll
            for (int jd = 0; jd < 4; jd++) oaccv[i][jd] = (f32x4){0.f, 0.f, 0.f, 0.f};

        int nchunk = pass ? 1 : 4;
        for (int jt = 0; jt < nchunk; jt++) {
            __syncthreads();
            if (pass == 0) {
                long base = (long)(b * 1152 + 128 + jt * 128);
#pragma unroll
                for (int t = 0; t < 4; t++) {
                    int e = tid + 256 * t; int j = e >> 3, c8 = (e & 7) * 8;
                    *(bf16x8*)&upool[j * 72 + c8] = *(const bf16x8*)&kb[(base + j) * 1024 + h * 64 + c8];
                }
#pragma unroll
                for (int t = 0; t < 4; t++) {
                    int e = tid + 256 * t; int d = e >> 4, j8 = (e & 15) * 8;
                    *(bf16x8*)&vt[d][j8] =
                        *(const bf16x8*)&vTb[((long)z * 64 + d) * 1152 + 128 + jt * 128 + j8];
                }
            } else {
#pragma unroll
                for (int t = 0; t < 4; t++) {
                    int e = tid + 256 * t; int j = e >> 3, c8 = (e & 7) * 8;
                    *(bf16x8*)&upool[j * 72 + c8] = *(const bf16x8*)&ckb[((long)(b * 128 + j)) * 1024 + h * 64 + c8];
                }
#pragma unroll
                for (int t = 0; t < 4; t++) {
                    int e = tid + 256 * t; int d = e >> 4, j8 = (e & 15) * 8;
                    *(bf16x8*)&vt[d][j8] = *(const bf16x8*)&cvT[((long)z * 64 + d) * 128 + j8];
                }
            }
            __syncthreads();

#pragma unroll
            for (int i = 0; i < 2; i++)
#pragma unroll
                for (int j = 0; j < 8; j++) sacc[i][j] = (f32x4){0.f, 0.f, 0.f, 0.f};
#pragma unroll
            for (int s = 0; s < 2; s++) {
                bf16x8 af[2], bfv[8];
#pragma unroll
                for (int i = 0; i < 2; i++)
                    af[i] = *(const bf16x8*)&qs[wid * 32 + i * 16 + fr][s * 32 + fq * 8];
#pragma unroll
                for (int j = 0; j < 8; j++)
                    bfv[j] = *(const bf16x8*)&upool[(j * 16 + fr) * 72 + s * 32 + fq * 8];
#pragma unroll
                for (int i = 0; i < 2; i++)
#pragma unroll
                    for (int j = 0; j < 8; j++)
                        sacc[i][j] = __builtin_amdgcn_mfma_f32_16x16x32_bf16(af[i], bfv[j], sacc[i][j], 0, 0, 0);
            }
            __syncthreads();

#pragma unroll
            for (int i = 0; i < 2; i++) {
#pragma unroll
                for (int g = 0; g < 4; g++) {
                    float mx = -3.4e38f;
#pragma unroll
                    for (int j = 0; j < 8; j++) mx = fmaxf(mx, sacc[i][j][g]);
                    mx *= 0.125f;
#pragma unroll
                    for (int msk = 1; msk <= 8; msk <<= 1) mx = fmaxf(mx, __shfl_xor(mx, msk, 64));
                    float mnew = fmaxf(mrow[i][g], mx);
                    float alpha = __expf(mrow[i][g] - mnew);
                    mrow[i][g] = mnew;
                    float sum = 0.f;
                    int prow = (wid * 32 + i * 16 + fq * 4 + g) * 136;
#pragma unroll
                    for (int j = 0; j < 8; j++) {
                        float p = __expf(sacc[i][j][g] * 0.125f - mnew);
                        sum += p;
                        upool[prow + j * 16 + fr] = (bf16)p;
                    }
#pragma unroll
                    for (int msk = 1; msk <= 8; msk <<= 1) sum += __shfl_xor(sum, msk, 16);
                    lrow[i][g] = lrow[i][g] * alpha + sum;
#pragma unroll
                    for (int jd = 0; jd < 4; jd++) oaccv[i][jd][g] *= alpha;
                }
            }
            __syncthreads();

#pragma unroll
            for (int s2 = 0; s2 < 4; s2++) {
                bf16x8 pa[2], vb[4];
#pragma unroll
                for (int i = 0; i < 2; i++)
                    pa[i] = *(const bf16x8*)&upool[(wid * 32 + i * 16 + fr) * 136 + s2 * 32 + fq * 8];
#pragma unroll
                for (int jd = 0; jd < 4; jd++)
                    vb[jd] = *(const bf16x8*)&vt[jd * 16 + fr][s2 * 32 + fq * 8];
#pragma unroll
                for (int i = 0; i < 2; i++)
#pragma unroll
                    for (int jd = 0; jd < 4; jd++)
                        oaccv[i][jd] = __builtin_amdgcn_mfma_f32_16x16x32_bf16(pa[i], vb[jd], oaccv[i][jd], 0, 0, 0);
            }
        }

        if (pass == 0) {
#pragma unroll
            for (int i = 0; i < 2; i++)
#pragma unroll
                for (int jd = 0; jd < 4; jd++)
#pragma unroll
                    for (int g = 0; g < 4; g++)
                        o1[i][jd][g] = oaccv[i][jd][g] / lrow[i][g];
        } else {
#pragma unroll
            for (int i = 0; i < 2; i++)
#pragma unroll
                for (int jd = 0; jd < 4; jd++)
#pragma unroll
                    for (int g = 0; g < 4; g++) {
                        float dd = o1[i][jd][g] - oaccv[i][jd][g] / lrow[i][g];
                        local += dd * dd;
                    }
        }
    }

#pragma unroll
    for (int off = 32; off; off >>= 1) local += __shfl_xor(local, off, 64);
    if (lane == 0) wred[wid] = local;
    __syncthreads();
    if (tid == 0)
        partials[(long)blockIdx.y * 4 + blockIdx.x] = wred[0] + wred[1] + wred[2] + wred[3];
}

__global__ __launch_bounds__(256)
void aux_reduce_kernel(const float* __restrict__ partials, float* __restrict__ out)
{
    int tid = threadIdx.x;
    __shared__ float wred[4];
    float s = 0.f;
    for (int i = tid; i < 512; i += 256) s += partials[i];
#pragma unroll
    for (int off = 32; off; off >>= 1) s += __shfl_xor(s, off, 64);
    if ((tid & 63) == 0) wred[tid >> 6] = s;
    __syncthreads();
    if (tid == 0) out[0] = (wred[0] + wred[1] + wred[2] + wred[3]) * (1.0f / 4194304.0f);
}

extern "C" void kernel_launch(void* const* d_in, const int* in_sizes, int n_in,
                              void* d_out, int out_size, void* d_ws, size_t ws_size,
                              hipStream_t stream)
{
    const float* x      = (const float*)d_in[0];
    const float* mem    = (const float*)d_in[1];
    const float* cmem   = (const float*)d_in[2];
    const float* pe     = (const float*)d_in[3];
    const float* Wq     = (const float*)d_in[4];
    const float* Wkv    = (const float*)d_in[5];
    const float* Wout   = (const float*)d_in[6];
    const float* bout   = (const float*)d_in[7];
    const float* conv_w = (const float*)d_in[8];
    const float* conv_b = (const float*)d_in[9];

    float* out_logits  = (float*)d_out;                 // 8*512*1024
    float* out_newmem  = out_logits + 4194304;          // 8*512*1024
    float* out_newcmem = out_newmem + 4194304;          // 8*128*1024
    float* out_aux     = out_newcmem + 1048576;         // 1
    float* out_weights = out_aux + 1;                   // 8*16*512*1152

    float* ws       = (float*)d_ws;
    float* partials = ws;                    // 4096 f
    float* pbuf     = partials + 4096;       // 4 * 1,048,576 f (split-K partials)
    bf16* bws     = (bf16*)(pbuf + 4194304);
    bf16* WqTb    = bws;                     // 1,048,576
    bf16* WkvTb   = WqTb + 1048576;          // 2,097,152
    bf16* WoutTb  = WkvTb + 2097152;         // 1,048,576
    bf16* convwTb = WoutTb + 1048576;        // 4,194,304
    bf16* vTb     = convwTb + 4194304;       // 9,437,184
    bf16* cvT     = vTb + 9437184;           // 1,048,576
    bf16* qb      = cvT + 1048576;           // 4,194,304
    bf16* kb      = qb + 4194304;            // 9,437,184
    bf16* ckb     = kb + 9437184;            // 1,048,576
    bf16* peb     = ckb + 1048576;           // 1,179,648
    bf16* xb      = peb + 1179648;           // 4,194,304
    bf16* memb    = xb + 4194304;            // 4,194,304
    bf16* cmemb   = memb + 4194304;          // 1,048,576
    bf16* ncmemb  = cmemb + 1048576;         // 1,048,576
    bf16* oatb    = ncmemb + 1048576;        // 4,194,304

    dim3 blk(256);

    transpose_cast<<<dim3(32, 32), blk, 0, stream>>>(Wq, WqTb, 1024, 1024);
    transpose_cast<<<dim3(64, 32), blk, 0, stream>>>(Wkv, WkvTb, 1024, 2048);
    transpose_cast<<<dim3(32, 32), blk, 0, stream>>>(Wout, WoutTb, 1024, 1024);
    convw_cast<<<dim3(1024), blk, 0, stream>>>(conv_w, convwTb);
    // merged input casts: pe | x (+NT mirror to new_mem) | mem | cmem
    cast_f2b_multi<<<dim3(2048), blk, 0, stream>>>(
        pe, peb, 294912, x, xb, 1048576, mem, memb, 1048576, cmem, cmemb, 262144,
        out_newmem);

    // qb = bf16(x @ Wq)
    mfma_gemm<0, 4><<<dim3(8, 32, 1), blk, 0, stream>>>(
        xb, WqTb, nullptr, qb, nullptr, 1024, 1024, 1024, 1024, 1024,
        nullptr, 0, nullptr, nullptr, nullptr);

    // kb/vTb = bf16(concat(cmem,mem,x) @ Wkv)
    mfma_gemm<1, 5><<<dim3(16, 72, 1), blk, 0, stream>>>(
        nullptr, WkvTb, nullptr, kb, vTb, 2048, 1024, 1024, 1024, 2048,
        nullptr, 1152, cmemb, memb, xb);

    // conv-compress GEMM, split-K: 4 slices of K=1024 -> fp32 partials
    mfma_gemm<0, 8><<<dim3(8, 8, 4), blk, 0, stream>>>(
        memb, convwTb, pbuf, nullptr, nullptr, 1024, 1024, 4096, 4096, 1024,
        nullptr, 0, nullptr, nullptr, nullptr);
    // reduce partials + bias -> new_cmem (fp32) + ncmemb (bf16)
    splitk_reduce<<<dim3(1024), blk, 0, stream>>>(pbuf, conv_b, out_newcmem, ncmemb);

    // ckb/cvT = bf16(new_cmem @ Wkv)
    mfma_gemm<0, 5><<<dim3(16, 8, 1), blk, 0, stream>>>(
        ncmemb, WkvTb, nullptr, ckb, cvT, 2048, 1024, 1024, 1024, 2048,
        nullptr, 128, nullptr, nullptr, nullptr);

    // fused attention with XCD-chunked swizzle
    attn_fused16<<<dim3(4096), blk, 0, stream>>>(qb, kb, peb, vTb, out_weights, oatb);

    // logits = oat @ Wout + bout (non-temporal output)
    mfma_gemm<0, 6><<<dim3(8, 32, 1), blk, 0, stream>>>(
        oatb, WoutTb, out_logits, nullptr, nullptr, 1024, 1024, 1024, 1024, 1024,
        bout, 0, nullptr, nullptr, nullptr);

    // aux loss
    aux_mfma_kernel<<<dim3(4, 128), blk, 0, stream>>>(qb, kb, ckb, vTb, cvT, partials);
    aux_reduce_kernel<<<dim3(1), blk, 0, stream>>>(partials, out_aux);
}